// Round 11
// baseline (2259.748 us; speedup 1.0000x reference)
//
#include <hip/hip_runtime.h>
#include <stdint.h>

#define S_LEN 2048
#define DM    768
#define NHEAD 8
#define HDIM  96
#define HDP   128
#define FF    3072
#define FF2   6144
#define NEXP  4
#define NTOK  4096
#define NBH   16
#define HBROWS (2 * NTOK)

typedef unsigned short u16;
typedef short bf16x8 __attribute__((ext_vector_type(8)));
typedef float f32x4 __attribute__((ext_vector_type(4)));
typedef __attribute__((address_space(1))) void* gptr_t;
typedef __attribute__((address_space(3))) void* lptr_t;

__device__ __forceinline__ u16 f2bf(float f) {
  union { float f; uint32_t u; } v; v.f = f;
  uint32_t r = v.u + 0x7FFFu + ((v.u >> 16) & 1u);
  return (u16)(r >> 16);
}
__device__ __forceinline__ float bf2f(u16 h) {
  union { uint32_t u; float f; } v; v.u = ((uint32_t)h) << 16;
  return v.f;
}
__device__ __forceinline__ void split2(float f, u16& hi, u16& lo) {
  u16 h = f2bf(f);
  lo = f2bf(f - bf2f(h));
  hi = h;
}
__device__ __forceinline__ float siluf(float g) {
  return g / (1.0f + expf(-g));
}
__device__ __forceinline__ void gload16(const void* g, void* l) {
  __builtin_amdgcn_global_load_lds((gptr_t)(void*)g, (lptr_t)l, 16, 0, 0);
}
// GEMM-tile LDS swizzle (64B rows): chunk bits 4-5 XOR row bits 1-2 (byte 7-8).
__device__ __forceinline__ int swz(int byte) {
  return byte ^ (((byte >> 7) & 3) << 4);
}

// ---------------------------------------------------------------------------
// Plain NT GEMM, 2-phase double-buffered. C[M,N] = A[M,K] @ B[N,K]^T.
// Grid: (M/128, N/128, batch*kspl). Row-blocks fastest -> B-panel L2 reuse.
// MODE: 0 f32, 2 bf16, 3 atomic f32, 5 fused gate/up silu -> hb bf16.
// ---------------------------------------------------------------------------
template<int MODE>
__global__ __launch_bounds__(256) void gemm_nt(
    const u16* __restrict__ A, const u16* __restrict__ B, void* __restrict__ Cv,
    int M, int N, int K, int lda, int ldb, long sA, long sB, long sC, int kspl,
    u16* __restrict__ hb)
{
  __shared__ u16 As[2][128 * 32];
  __shared__ u16 Bs[2][128 * 32];
  const int z = blockIdx.z;
  const int bh = z / kspl;
  const int kc = z - bh * kspl;
  const u16* Az = A + (long)bh * sA;
  const u16* Bz = B + (long)bh * sB;
  const int brow = blockIdx.x << 7;
  const int bcol = blockIdx.y << 7;
  const int tid = threadIdx.x;
  const int wid = tid >> 6;
  const int lane = tid & 63;
  const int wr = (wid >> 1) << 6;
  const int wc = (wid & 1) << 6;

  f32x4 acc[4][4] = {};
  const int a0 = (wid << 11) + (lane << 4);

  auto stage = [&](int buf, int k0) {
#pragma unroll
    for (int c = 0; c < 2; ++c) {
      int ab = a0 + (c << 10);
      int lb = swz(ab);
      int row = ab >> 6;
      int kcol = (lb & 63) >> 1;
      int ld = (wid << 11) + (c << 10);
      gload16(Az + (long)(brow + row) * lda + (k0 + kcol), (char*)As[buf] + ld);
      gload16(Bz + (long)(bcol + row) * ldb + (k0 + kcol), (char*)Bs[buf] + ld);
    }
  };

  const int kt = K / kspl;
  const int kbeg = kc * kt;
  const int nt = kt >> 5;
  stage(0, kbeg);
  __syncthreads();
  for (int t = 0; t < nt; ++t) {
    const int cur = t & 1;
    if (t + 1 < nt) stage(cur ^ 1, kbeg + ((t + 1) << 5));
    bf16x8 af[4], bfr[4];
    const int lr = lane & 15;
    const int lk = (lane >> 4) << 4;
#pragma unroll
    for (int m = 0; m < 4; ++m)
      af[m] = *(const bf16x8*)((const char*)As[cur] + swz((((wr + m * 16 + lr) << 6) + lk)));
#pragma unroll
    for (int n = 0; n < 4; ++n)
      bfr[n] = *(const bf16x8*)((const char*)Bs[cur] + swz((((wc + n * 16 + lr) << 6) + lk)));
#pragma unroll
    for (int m = 0; m < 4; ++m)
#pragma unroll
      for (int n = 0; n < 4; ++n)
        acc[m][n] = __builtin_amdgcn_mfma_f32_16x16x32_bf16(af[m], bfr[n], acc[m][n], 0, 0, 0);
    if (t + 1 < nt) __syncthreads();
  }

  const int crow0 = brow + wr + ((lane >> 4) << 2);
  const int ccol0 = bcol + wc + (lane & 15);
  const long cbase = (long)bh * sC;
  if constexpr (MODE == 5) {
    const int pbase = (bcol + wc) >> 5;
#pragma unroll
    for (int m = 0; m < 4; ++m)
#pragma unroll
      for (int np = 0; np < 2; ++np)
#pragma unroll
        for (int j = 0; j < 4; ++j) {
          int r = crow0 + m * 16 + j;
          float g = acc[m][2 * np][j], u = acc[m][2 * np + 1][j];
          int hcol = ((pbase + np) << 4) + (lane & 15);
          hb[(long)r * FF + hcol] = f2bf(siluf(g) * u);
        }
  } else {
#pragma unroll
    for (int m = 0; m < 4; ++m)
#pragma unroll
      for (int n = 0; n < 4; ++n)
#pragma unroll
        for (int j = 0; j < 4; ++j) {
          long idx = cbase + (long)(crow0 + m * 16 + j) * N + (ccol0 + n * 16);
          float v = acc[m][n][j];
          if constexpr (MODE == 2) ((u16*)Cv)[idx] = f2bf(v);
          else if constexpr (MODE == 3) unsafeAtomicAdd((float*)Cv + idx, v);
          else ((float*)Cv)[idx] = v;
        }
  }
}

// ---------------------------------------------------------------------------
// Split (bf16x3) NT GEMM, dense. MODE: 0 f32, 3 atomic f32, 5 fused gu silu.
// Grid: (M/128, N/128, batch*kspl).
// ---------------------------------------------------------------------------
template<int MODE>
__global__ __launch_bounds__(256) void gemm3_nt(
    const u16* __restrict__ Ah, const u16* __restrict__ Al,
    const u16* __restrict__ Bh, const u16* __restrict__ Bl,
    float* __restrict__ C,
    int M, int N, int K, int lda, int ldb, long sA, long sB, long sC, int kspl,
    u16* __restrict__ hbh, u16* __restrict__ hbl)
{
  __shared__ u16 Ash[2][128 * 32], Asl[2][128 * 32];
  __shared__ u16 Bsh[2][128 * 32], Bsl[2][128 * 32];
  const int z = blockIdx.z;
  const int bh = z / kspl;
  const int kc = z - bh * kspl;
  const u16* Azh = Ah + (long)bh * sA;
  const u16* Azl = Al + (long)bh * sA;
  const u16* Bzh = Bh + (long)bh * sB;
  const u16* Bzl = Bl + (long)bh * sB;
  const int brow = blockIdx.x << 7;
  const int bcol = blockIdx.y << 7;
  const int tid = threadIdx.x;
  const int wid = tid >> 6;
  const int lane = tid & 63;
  const int wr = (wid >> 1) << 6;
  const int wc = (wid & 1) << 6;

  f32x4 acc[4][4] = {};
  const int a0 = (wid << 11) + (lane << 4);

  auto stage = [&](int buf, int k0) {
#pragma unroll
    for (int c = 0; c < 2; ++c) {
      int ab = a0 + (c << 10);
      int lb = swz(ab);
      int row = ab >> 6;
      int kcol = (lb & 63) >> 1;
      long ao = (long)(brow + row) * lda + (k0 + kcol);
      long bo = (long)(bcol + row) * ldb + (k0 + kcol);
      int ld = (wid << 11) + (c << 10);
      gload16(Azh + ao, (char*)Ash[buf] + ld);
      gload16(Azl + ao, (char*)Asl[buf] + ld);
      gload16(Bzh + bo, (char*)Bsh[buf] + ld);
      gload16(Bzl + bo, (char*)Bsl[buf] + ld);
    }
  };

  const int kt = K / kspl;
  const int kbeg = kc * kt;
  const int nt = kt >> 5;
  stage(0, kbeg);
  __syncthreads();
  for (int t = 0; t < nt; ++t) {
    const int cur = t & 1;
    if (t + 1 < nt) stage(cur ^ 1, kbeg + ((t + 1) << 5));
    const int lr = lane & 15;
    const int lk = (lane >> 4) << 4;
    bf16x8 ah[4], al[4], bh_[4], bl[4];
#pragma unroll
    for (int m = 0; m < 4; ++m) {
      int off = swz(((wr + m * 16 + lr) << 6) + lk);
      ah[m] = *(const bf16x8*)((const char*)Ash[cur] + off);
      al[m] = *(const bf16x8*)((const char*)Asl[cur] + off);
    }
#pragma unroll
    for (int n = 0; n < 4; ++n) {
      int off = swz(((wc + n * 16 + lr) << 6) + lk);
      bh_[n] = *(const bf16x8*)((const char*)Bsh[cur] + off);
      bl[n] = *(const bf16x8*)((const char*)Bsl[cur] + off);
    }
#pragma unroll
    for (int m = 0; m < 4; ++m)
#pragma unroll
      for (int n = 0; n < 4; ++n) {
        acc[m][n] = __builtin_amdgcn_mfma_f32_16x16x32_bf16(al[m], bh_[n], acc[m][n], 0, 0, 0);
        acc[m][n] = __builtin_amdgcn_mfma_f32_16x16x32_bf16(ah[m], bl[n], acc[m][n], 0, 0, 0);
        acc[m][n] = __builtin_amdgcn_mfma_f32_16x16x32_bf16(ah[m], bh_[n], acc[m][n], 0, 0, 0);
      }
    if (t + 1 < nt) __syncthreads();
  }

  const int crow0 = brow + wr + ((lane >> 4) << 2);
  const int ccol0 = bcol + wc + (lane & 15);
  const long cbase = (long)bh * sC;
  if constexpr (MODE == 5) {
    const int pbase = (bcol + wc) >> 5;
#pragma unroll
    for (int m = 0; m < 4; ++m)
#pragma unroll
      for (int np = 0; np < 2; ++np)
#pragma unroll
        for (int j = 0; j < 4; ++j) {
          int r = crow0 + m * 16 + j;
          float g = acc[m][2 * np][j], u = acc[m][2 * np + 1][j];
          float h = siluf(g) * u;
          int hcol = ((pbase + np) << 4) + (lane & 15);
          u16 hh, ll; split2(h, hh, ll);
          hbh[(long)r * FF + hcol] = hh;
          hbl[(long)r * FF + hcol] = ll;
        }
  } else {
#pragma unroll
    for (int m = 0; m < 4; ++m)
#pragma unroll
      for (int n = 0; n < 4; ++n)
#pragma unroll
        for (int j = 0; j < 4; ++j) {
          long idx = cbase + (long)(crow0 + m * 16 + j) * N + (ccol0 + n * 16);
          if constexpr (MODE == 3) unsafeAtomicAdd(&C[idx], acc[m][n][j]);
          else C[idx] = acc[m][n][j];
        }
  }
}

// ---------------------------------------------------------------------------
// Batched indirect split GEMM over experts (blockIdx.z = e*kspl+kc).
// Grid: (Mmax/128, N/128, NEXP*kspl).
// MODE 5: gather-A via perm[e], fused gu silu * comb -> hb rows cbase[e]+r.
// MODE 1: compact-A rows cbase[e]+r (clamped), scatter-atomic f32.
// ---------------------------------------------------------------------------
template<int MODE>
__global__ __launch_bounds__(256) void gemm3i_nt(
    const u16* __restrict__ Ah, const u16* __restrict__ Al,
    const u16* __restrict__ Bh, const u16* __restrict__ Bl,
    float* __restrict__ C, int N, int K, int lda, int ldb, int ldc,
    const int* __restrict__ perm, const int* __restrict__ cnt,
    const int* __restrict__ cbase, int kspl, long wstride,
    u16* __restrict__ hbh, u16* __restrict__ hbl, const float* __restrict__ comb)
{
  const int z = blockIdx.z;
  const int e = z / kspl;
  const int kc = z - e * kspl;
  const int cn = cnt[e];
  const int brow = blockIdx.x << 7;
  if (brow >= cn) return;
  const int cb = cbase[e];
  const int* pe = perm + e * NTOK;
  const u16* Bhe = Bh + (long)e * wstride;
  const u16* Ble = Bl + (long)e * wstride;
  __shared__ u16 Ash[2][128 * 32], Asl[2][128 * 32];
  __shared__ u16 Bsh[2][128 * 32], Bsl[2][128 * 32];
  const int bcol = blockIdx.y << 7;
  const int tid = threadIdx.x;
  const int wid = tid >> 6;
  const int lane = tid & 63;
  const int wr = (wid >> 1) << 6;
  const int wc = (wid & 1) << 6;

  f32x4 acc[4][4] = {};
  const int a0 = (wid << 11) + (lane << 4);

  int arow[2];
#pragma unroll
  for (int c = 0; c < 2; ++c) {
    int ab = a0 + (c << 10);
    int row = ab >> 6;
    int g = brow + row;
    if constexpr (MODE == 5) {
      arow[c] = (g < cn) ? pe[g] : pe[brow];
    } else {
      arow[c] = cb + ((g < cn) ? g : (cn - 1));
    }
  }

  auto stage = [&](int buf, int k0) {
#pragma unroll
    for (int c = 0; c < 2; ++c) {
      int ab = a0 + (c << 10);
      int lb = swz(ab);
      int row = ab >> 6;
      int kcol = (lb & 63) >> 1;
      int ld = (wid << 11) + (c << 10);
      gload16(Ah + (long)arow[c] * lda + (k0 + kcol), (char*)Ash[buf] + ld);
      gload16(Al + (long)arow[c] * lda + (k0 + kcol), (char*)Asl[buf] + ld);
      long bo = (long)(bcol + row) * ldb + (k0 + kcol);
      gload16(Bhe + bo, (char*)Bsh[buf] + ld);
      gload16(Ble + bo, (char*)Bsl[buf] + ld);
    }
  };

  const int kt = K / kspl;
  const int kbeg = kc * kt;
  const int nt = kt >> 5;
  stage(0, kbeg);
  __syncthreads();
  for (int t = 0; t < nt; ++t) {
    const int cur = t & 1;
    if (t + 1 < nt) stage(cur ^ 1, kbeg + ((t + 1) << 5));
    const int lr = lane & 15;
    const int lk = (lane >> 4) << 4;
    bf16x8 ah[4], al[4], bh_[4], bl[4];
#pragma unroll
    for (int m = 0; m < 4; ++m) {
      int off = swz(((wr + m * 16 + lr) << 6) + lk);
      ah[m] = *(const bf16x8*)((const char*)Ash[cur] + off);
      al[m] = *(const bf16x8*)((const char*)Asl[cur] + off);
    }
#pragma unroll
    for (int n = 0; n < 4; ++n) {
      int off = swz(((wc + n * 16 + lr) << 6) + lk);
      bh_[n] = *(const bf16x8*)((const char*)Bsh[cur] + off);
      bl[n] = *(const bf16x8*)((const char*)Bsl[cur] + off);
    }
#pragma unroll
    for (int m = 0; m < 4; ++m)
#pragma unroll
      for (int n = 0; n < 4; ++n) {
        acc[m][n] = __builtin_amdgcn_mfma_f32_16x16x32_bf16(al[m], bh_[n], acc[m][n], 0, 0, 0);
        acc[m][n] = __builtin_amdgcn_mfma_f32_16x16x32_bf16(ah[m], bl[n], acc[m][n], 0, 0, 0);
        acc[m][n] = __builtin_amdgcn_mfma_f32_16x16x32_bf16(ah[m], bh_[n], acc[m][n], 0, 0, 0);
      }
    if (t + 1 < nt) __syncthreads();
  }

  const int crow0 = brow + wr + ((lane >> 4) << 2);
  const int ccol0 = bcol + wc + (lane & 15);
  if constexpr (MODE == 5) {
    const int pbase = (bcol + wc) >> 5;
#pragma unroll
    for (int m = 0; m < 4; ++m)
#pragma unroll
      for (int j = 0; j < 4; ++j) {
        int r = crow0 + m * 16 + j;
        if (r < cn) {
          float w = comb[pe[r] * 4 + e];
#pragma unroll
          for (int np = 0; np < 2; ++np) {
            float g = acc[m][2 * np][j], u = acc[m][2 * np + 1][j];
            float h = siluf(g) * u * w;
            int hcol = ((pbase + np) << 4) + (lane & 15);
            u16 hh, ll; split2(h, hh, ll);
            hbh[(long)(cb + r) * FF + hcol] = hh;
            hbl[(long)(cb + r) * FF + hcol] = ll;
          }
        }
      }
  } else {
#pragma unroll
    for (int m = 0; m < 4; ++m)
#pragma unroll
      for (int n = 0; n < 4; ++n)
#pragma unroll
        for (int j = 0; j < 4; ++j) {
          int r = crow0 + m * 16 + j;
          if (r < cn) {
            int col = ccol0 + n * 16;
            unsafeAtomicAdd(&C[(long)pe[r] * ldc + col], acc[m][n][j]);
          }
        }
  }
}

// ---------------------------------------------------------------------------
// Batched indirect plain bf16 GEMM over experts (layer-1).
// MODE 5: gather-A, fused gu -> hb rows cbase[e]+r. MODE 3: compact-A, scatter.
// ---------------------------------------------------------------------------
template<int MODE>
__global__ __launch_bounds__(256) void gemmi_nt(
    const u16* __restrict__ A, const u16* __restrict__ B, void* __restrict__ Cv,
    int N, int K, int lda, int ldb, int ldc,
    const int* __restrict__ perm, const int* __restrict__ cnt,
    const int* __restrict__ cbase, int kspl, long wstride,
    u16* __restrict__ hb, const float* __restrict__ comb)
{
  const int z = blockIdx.z;
  const int e = z / kspl;
  const int kc = z - e * kspl;
  const int cn = cnt[e];
  const int brow = blockIdx.x << 7;
  if (brow >= cn) return;
  const int cb = cbase[e];
  const int* pe = perm + e * NTOK;
  const u16* Be = B + (long)e * wstride;
  __shared__ u16 As[2][128 * 32];
  __shared__ u16 Bs[2][128 * 32];
  const int bcol = blockIdx.y << 7;
  const int tid = threadIdx.x;
  const int wid = tid >> 6;
  const int lane = tid & 63;
  const int wr = (wid >> 1) << 6;
  const int wc = (wid & 1) << 6;

  f32x4 acc[4][4] = {};
  const int a0 = (wid << 11) + (lane << 4);

  int arow[2];
#pragma unroll
  for (int c = 0; c < 2; ++c) {
    int ab = a0 + (c << 10);
    int row = ab >> 6;
    int g = brow + row;
    if constexpr (MODE == 5) {
      arow[c] = (g < cn) ? pe[g] : pe[brow];
    } else {
      arow[c] = cb + ((g < cn) ? g : (cn - 1));
    }
  }

  auto stage = [&](int buf, int k0) {
#pragma unroll
    for (int c = 0; c < 2; ++c) {
      int ab = a0 + (c << 10);
      int lb = swz(ab);
      int row = ab >> 6;
      int kcol = (lb & 63) >> 1;
      int ld = (wid << 11) + (c << 10);
      gload16(A + (long)arow[c] * lda + (k0 + kcol), (char*)As[buf] + ld);
      gload16(Be + (long)(bcol + row) * ldb + (k0 + kcol), (char*)Bs[buf] + ld);
    }
  };

  const int kt = K / kspl;
  const int kbeg = kc * kt;
  const int nt = kt >> 5;
  stage(0, kbeg);
  __syncthreads();
  for (int t = 0; t < nt; ++t) {
    const int cur = t & 1;
    if (t + 1 < nt) stage(cur ^ 1, kbeg + ((t + 1) << 5));
    bf16x8 af[4], bfr[4];
    const int lr = lane & 15;
    const int lk = (lane >> 4) << 4;
#pragma unroll
    for (int m = 0; m < 4; ++m)
      af[m] = *(const bf16x8*)((const char*)As[cur] + swz((((wr + m * 16 + lr) << 6) + lk)));
#pragma unroll
    for (int n = 0; n < 4; ++n)
      bfr[n] = *(const bf16x8*)((const char*)Bs[cur] + swz((((wc + n * 16 + lr) << 6) + lk)));
#pragma unroll
    for (int m = 0; m < 4; ++m)
#pragma unroll
      for (int n = 0; n < 4; ++n)
        acc[m][n] = __builtin_amdgcn_mfma_f32_16x16x32_bf16(af[m], bfr[n], acc[m][n], 0, 0, 0);
    if (t + 1 < nt) __syncthreads();
  }

  const int crow0 = brow + wr + ((lane >> 4) << 2);
  const int ccol0 = bcol + wc + (lane & 15);
  if constexpr (MODE == 5) {
    const int pbase = (bcol + wc) >> 5;
#pragma unroll
    for (int m = 0; m < 4; ++m)
#pragma unroll
      for (int j = 0; j < 4; ++j) {
        int r = crow0 + m * 16 + j;
        if (r < cn) {
          float w = comb[pe[r] * 4 + e];
#pragma unroll
          for (int np = 0; np < 2; ++np) {
            float g = acc[m][2 * np][j], u = acc[m][2 * np + 1][j];
            int hcol = ((pbase + np) << 4) + (lane & 15);
            hb[(long)(cb + r) * FF + hcol] = f2bf(siluf(g) * u * w);
          }
        }
      }
  } else {
#pragma unroll
    for (int m = 0; m < 4; ++m)
#pragma unroll
      for (int n = 0; n < 4; ++n)
#pragma unroll
        for (int j = 0; j < 4; ++j) {
          int r = crow0 + m * 16 + j;
          if (r < cn) {
            int col = ccol0 + n * 16;
            unsafeAtomicAdd((float*)Cv + (long)pe[r] * ldc + col, acc[m][n][j]);
          }
        }
  }
}

// ---------------------------------------------------------------------------
// Fused flash attention. QK computed over exact K=96 (pad cols are zero).
// ---------------------------------------------------------------------------
__global__ __launch_bounds__(256, 2) void fattn_k(
    const u16* __restrict__ qh, const u16* __restrict__ ql,
    const u16* __restrict__ kh, const u16* __restrict__ kl,
    const u16* __restrict__ vth, const u16* __restrict__ vtl,
    u16* __restrict__ omh, u16* __restrict__ oml, float scale)
{
  __shared__ u16 Ksh[64 * 128], Ksl[64 * 128];
  __shared__ u16 Vsh[128 * 64], Vsl[128 * 64];
  const int bh = blockIdx.x;
  const int qt = blockIdx.y;
  const int tid = threadIdx.x, wid = tid >> 6, lane = tid & 63;
  const int lr = lane & 15, lg = lane >> 4;
  const int q0 = qt * 64 + wid * 16;
  const long bhoff = (long)bh * S_LEN * HDP;
  const u16* Qh = qh + bhoff;  const u16* Ql = ql + bhoff;
  const u16* Kgh = kh + bhoff; const u16* Kgl = kl + bhoff;
  const u16* Vgh = vth + bhoff; const u16* Vgl = vtl + bhoff;

  bf16x8 qfh[3], qfl[3];
#pragma unroll
  for (int kk = 0; kk < 3; ++kk) {
    long o = (long)(q0 + lr) * HDP + kk * 32 + lg * 8;
    qfh[kk] = *(const bf16x8*)(Qh + o);
    qfl[kk] = *(const bf16x8*)(Ql + o);
  }

  f32x4 oacc[6] = {};
  float rm[4], rls[4];
#pragma unroll
  for (int j = 0; j < 4; ++j) { rm[j] = -1e30f; rls[j] = 0.f; }

  for (int t = 0; t < S_LEN / 64; ++t) {
    __syncthreads();
#pragma unroll
    for (int c = 0; c < 4; ++c) {
      int off = (tid + (c << 8)) << 4;
      {
        int lb = off ^ ((((off >> 8) & 7)) << 4);
        int row = lb >> 8, colh = (lb & 255) >> 1;
        long src = (long)(t * 64 + row) * HDP + colh;
        gload16(Kgh + src, (char*)Ksh + off);
        gload16(Kgl + src, (char*)Ksl + off);
      }
      {
        int lb = off ^ ((((off >> 7) & 7)) << 4);
        int row = lb >> 7, colh = (lb & 127) >> 1;
        long src = (long)row * S_LEN + t * 64 + colh;
        gload16(Vgh + src, (char*)Vsh + off);
        gload16(Vgl + src, (char*)Vsl + off);
      }
    }
    __syncthreads();

    f32x4 sacc[4] = {};
#pragma unroll
    for (int kk = 0; kk < 3; ++kk) {
      bf16x8 kbh[4], kbl[4];
#pragma unroll
      for (int n = 0; n < 4; ++n) {
        int byte = ((n * 16 + lr) << 8) + (kk << 6) + (lg << 4);
        byte ^= ((byte >> 8) & 7) << 4;
        kbh[n] = *(const bf16x8*)((const char*)Ksh + byte);
        kbl[n] = *(const bf16x8*)((const char*)Ksl + byte);
      }
      __builtin_amdgcn_s_setprio(1);
#pragma unroll
      for (int n = 0; n < 4; ++n) {
        sacc[n] = __builtin_amdgcn_mfma_f32_16x16x32_bf16(qfl[kk], kbh[n], sacc[n], 0, 0, 0);
        sacc[n] = __builtin_amdgcn_mfma_f32_16x16x32_bf16(qfh[kk], kbl[n], sacc[n], 0, 0, 0);
        sacc[n] = __builtin_amdgcn_mfma_f32_16x16x32_bf16(qfh[kk], kbh[n], sacc[n], 0, 0, 0);
      }
      __builtin_amdgcn_s_setprio(0);
    }
    __syncthreads();

#pragma unroll
    for (int j = 0; j < 4; ++j) {
      float mx = fmaxf(fmaxf(sacc[0][j], sacc[1][j]),
                       fmaxf(sacc[2][j], sacc[3][j])) * scale;
      mx = fmaxf(mx, __shfl_xor(mx, 1));
      mx = fmaxf(mx, __shfl_xor(mx, 2));
      mx = fmaxf(mx, __shfl_xor(mx, 4));
      mx = fmaxf(mx, __shfl_xor(mx, 8));
      float mnew = fmaxf(rm[j], mx);
      float corr = __expf(rm[j] - mnew);
      rm[j] = mnew;
      float ps = 0.f;
#pragma unroll
      for (int n = 0; n < 4; ++n) {
        float p = __expf(sacc[n][j] * scale - mnew);
        sacc[n][j] = p; ps += p;
      }
      ps += __shfl_xor(ps, 1); ps += __shfl_xor(ps, 2);
      ps += __shfl_xor(ps, 4); ps += __shfl_xor(ps, 8);
      rls[j] = rls[j] * corr + ps;
#pragma unroll
      for (int n2 = 0; n2 < 6; ++n2) oacc[n2][j] *= corr;
    }

    char* Pwh = (char*)Ksh + (wid << 11);
    char* Pwl = (char*)Ksl + (wid << 11);
#pragma unroll
    for (int n = 0; n < 4; ++n)
#pragma unroll
      for (int j = 0; j < 4; ++j) {
        int row = lg * 4 + j;
        int byte = (row << 7) + ((n * 16 + lr) << 1);
        byte ^= ((byte >> 7) & 7) << 4;
        u16 h, l; split2(sacc[n][j], h, l);
        *(u16*)(Pwh + byte) = h;
        *(u16*)(Pwl + byte) = l;
      }
    bf16x8 pah[2], pal[2];
#pragma unroll
    for (int kk = 0; kk < 2; ++kk) {
      int byte = (lr << 7) + (kk << 6) + (lg << 4);
      byte ^= ((byte >> 7) & 7) << 4;
      pah[kk] = *(const bf16x8*)(Pwh + byte);
      pal[kk] = *(const bf16x8*)(Pwl + byte);
    }

#pragma unroll
    for (int kk = 0; kk < 2; ++kk) {
      bf16x8 vbh[6], vbl[6];
#pragma unroll
      for (int n2 = 0; n2 < 6; ++n2) {
        int byte = ((n2 * 16 + lr) << 7) + (kk << 6) + (lg << 4);
        byte ^= ((byte >> 7) & 7) << 4;
        vbh[n2] = *(const bf16x8*)((const char*)Vsh + byte);
        vbl[n2] = *(const bf16x8*)((const char*)Vsl + byte);
      }
      __builtin_amdgcn_s_setprio(1);
#pragma unroll
      for (int n2 = 0; n2 < 6; ++n2) {
        oacc[n2] = __builtin_amdgcn_mfma_f32_16x16x32_bf16(pal[kk], vbh[n2], oacc[n2], 0, 0, 0);
        oacc[n2] = __builtin_amdgcn_mfma_f32_16x16x32_bf16(pah[kk], vbl[n2], oacc[n2], 0, 0, 0);
        oacc[n2] = __builtin_amdgcn_mfma_f32_16x16x32_bf16(pah[kk], vbh[n2], oacc[n2], 0, 0, 0);
      }
      __builtin_amdgcn_s_setprio(0);
    }
  }

  const int b = bh >> 3, h = bh & 7;
#pragma unroll
  for (int j = 0; j < 4; ++j) {
    float inv = 1.0f / rls[j];
    int q = q0 + lg * 4 + j;
    long base = ((long)(b * S_LEN + q)) * DM + h * HDIM;
#pragma unroll
    for (int n2 = 0; n2 < 6; ++n2) {
      int d = n2 * 16 + lr;
      u16 hh, ll; split2(oacc[n2][j] * inv, hh, ll);
      omh[base + d] = hh; oml[base + d] = ll;
    }
  }
}

// ---------------------------------------------------------------------------
// fp32 [R][C] -> bf16 hi/lo [C][R] transpose+split, z-batched.
// ilv<0: linear rows; ilv in {0,1}: gate/up 16-row interleave. outl optional.
// ---------------------------------------------------------------------------
__global__ void wconv_t(const float* __restrict__ in, u16* __restrict__ outh,
                        u16* __restrict__ outl, int R, int C, int ilv,
                        long inStride, long outStride) {
  __shared__ float tile[32][33];
  long z = blockIdx.z;
  in += z * inStride; outh += z * outStride;
  if (outl) outl += z * outStride;
  int c0 = blockIdx.x << 5, r0 = blockIdx.y << 5;
  int tx = threadIdx.x;
  for (int rr = threadIdx.y; rr < 32; rr += 8)
    tile[rr][tx] = in[(long)(r0 + rr) * C + (c0 + tx)];
  __syncthreads();
  for (int rr = threadIdx.y; rr < 32; rr += 8) {
    u16 h, l; split2(tile[tx][rr], h, l);
    int f = c0 + rr;
    long orow = (ilv < 0) ? f : (((f >> 4) << 5) + (ilv << 4) + (f & 15));
    long o = orow * R + (r0 + tx);
    outh[o] = h;
    if (outl) outl[o] = l;
  }
}

__global__ __launch_bounds__(256) void ln_k(const float* __restrict__ in,
    const float* __restrict__ g, const float* __restrict__ b,
    float* __restrict__ outf, u16* __restrict__ outh, u16* __restrict__ outl) {
  int row = blockIdx.x;
  const float* x = in + (long)row * DM;
  int tid = threadIdx.x;
  float v[3], s = 0.f, ss = 0.f;
#pragma unroll
  for (int i = 0; i < 3; ++i) { v[i] = x[tid + (i << 8)]; s += v[i]; ss += v[i] * v[i]; }
  __shared__ float red[2][4];
  for (int o = 32; o; o >>= 1) { s += __shfl_down(s, o); ss += __shfl_down(ss, o); }
  int wid = tid >> 6, lane = tid & 63;
  if (!lane) { red[0][wid] = s; red[1][wid] = ss; }
  __syncthreads();
  s = red[0][0] + red[0][1] + red[0][2] + red[0][3];
  ss = red[1][0] + red[1][1] + red[1][2] + red[1][3];
  float mean = s * (1.f / DM);
  float var = ss * (1.f / DM) - mean * mean;
  float rs = rsqrtf(var + 1e-5f);
#pragma unroll
  for (int i = 0; i < 3; ++i) {
    int c = tid + (i << 8);
    float y = (v[i] - mean) * rs * g[c] + b[c];
    if (outf) outf[(long)row * DM + c] = y;
    if (outh) { u16 h, l; split2(y, h, l); outh[(long)row * DM + c] = h; outl[(long)row * DM + c] = l; }
  }
}

__global__ void rope_tables_k(float* __restrict__ cosT, float* __restrict__ sinT) {
  int s = blockIdx.x, d = threadIdx.x;
  int xc = s & 15, y = (s >> 4) & 15, t = s >> 8;
  int axis = d / 32, fi = d & 15;
  int coord = axis == 0 ? xc : (axis == 1 ? y : t);
  float inv = powf(10000.0f, -(float)fi / 16.0f);
  float ang = (float)coord * inv;
  cosT[s * HDIM + d] = cosf(ang);
  sinT[s * HDIM + d] = sinf(ang);
}

__global__ __launch_bounds__(256) void rope_apply_k(const float* __restrict__ qkv,
    const float* __restrict__ cosT, const float* __restrict__ sinT,
    u16* __restrict__ qh, u16* __restrict__ ql,
    u16* __restrict__ kh, u16* __restrict__ kl) {
  int bs = blockIdx.x;
  int b = bs >> 11, s = bs & 2047;
  const float* base = qkv + ((long)(b * S_LEN + s) * 3) * DM;
  for (int idx = threadIdx.x; idx < DM; idx += 256) {
    int h = idx / HDIM, d = idx - h * HDIM;
    float c = cosT[s * HDIM + d], sn = sinT[s * HDIM + d];
    int pair = (d < 48) ? idx + 48 : idx - 48;
    float qv = base[idx], kv = base[DM + idx];
    float qr = (d < 48) ? -base[pair] : base[pair];
    float kr = (d < 48) ? -base[DM + pair] : base[DM + pair];
    long o = ((long)(b * NHEAD + h) * S_LEN + s) * HDP + d;
    u16 hh, ll;
    split2(qv * c + qr * sn, hh, ll); qh[o] = hh; ql[o] = ll;
    split2(kv * c + kr * sn, hh, ll); kh[o] = hh; kl[o] = ll;
  }
  int t = threadIdx.x;
  int h = t >> 5, d = HDIM + (t & 31);
  long o = ((long)(b * NHEAD + h) * S_LEN + s) * HDP + d;
  qh[o] = 0; ql[o] = 0; kh[o] = 0; kl[o] = 0;
}

__global__ void v_transpose_k(const float* __restrict__ qkv,
                              u16* __restrict__ vh, u16* __restrict__ vl) {
  __shared__ float tile[32][33];
  int bh = blockIdx.z, b = bh >> 3, h = bh & 7;
  int s0 = blockIdx.x << 5, d0 = blockIdx.y << 5;
  int tx = threadIdx.x;
  for (int r = threadIdx.y; r < 32; r += 8) {
    int s = s0 + r, d = d0 + tx;
    float v = 0.f;
    if (d < HDIM) v = qkv[((long)(b * S_LEN + s) * 3 + 2) * DM + h * HDIM + d];
    tile[r][tx] = v;
  }
  __syncthreads();
  for (int r = threadIdx.y; r < 32; r += 8) {
    int d = d0 + r;
    u16 hh, ll; split2(tile[tx][r], hh, ll);
    long o = ((long)bh * HDP + d) * S_LEN + (s0 + tx);
    vh[o] = hh; vl[o] = ll;
  }
}

// Router: comb[tok][e] + top-2 bitmask per token.
__global__ __launch_bounds__(256) void router_k(const float* __restrict__ x,
    const float* __restrict__ gw, float* __restrict__ comb, int* __restrict__ mask) {
  int tok = blockIdx.x * 4 + (threadIdx.x >> 6);
  int lane = threadIdx.x & 63;
  const float* xr = x + (long)tok * DM;
  float a0 = 0, a1 = 0, a2 = 0, a3 = 0;
  for (int i = lane; i < DM; i += 64) {
    float xv = xr[i];
    const float* g = gw + i * 4;
    a0 += xv * g[0]; a1 += xv * g[1]; a2 += xv * g[2]; a3 += xv * g[3];
  }
  for (int o = 32; o; o >>= 1) {
    a0 += __shfl_down(a0, o); a1 += __shfl_down(a1, o);
    a2 += __shfl_down(a2, o); a3 += __shfl_down(a3, o);
  }
  if (lane == 0) {
    float p[4] = {a0, a1, a2, a3};
    float mx = fmaxf(fmaxf(p[0], p[1]), fmaxf(p[2], p[3]));
    float s = 0.f;
    for (int e = 0; e < 4; ++e) { p[e] = expf(p[e] - mx); s += p[e]; }
    for (int e = 0; e < 4; ++e) p[e] /= s;
    int i1 = 0;
    for (int e = 1; e < 4; ++e) if (p[e] > p[i1]) i1 = e;
    int i2 = -1;
    for (int e = 0; e < 4; ++e) if (e != i1 && (i2 < 0 || p[e] > p[i2])) i2 = e;
    float ssum = p[i1] + p[i2] + 1e-5f;
    float out[4] = {0, 0, 0, 0};
    out[i1] = p[i1] / ssum; out[i2] = p[i2] / ssum;
    for (int e = 0; e < 4; ++e) comb[tok * 4 + e] = out[e];
    mask[tok] = (1 << i1) | (1 << i2);
  }
}

// Deterministic per-expert compaction; one block per expert (grid = NEXP).
__global__ void scan_k(const int* __restrict__ mask, int* __restrict__ perm,
                       int* __restrict__ cnt) {
  __shared__ int sd[256];
  __shared__ int base;
  int tid = threadIdx.x;
  int e = blockIdx.x;
  if (tid == 0) base = 0;
  __syncthreads();
  for (int c = 0; c < NTOK / 256; ++c) {
    int tok = c * 256 + tid;
    int f = (mask[tok] >> e) & 1;
    sd[tid] = f;
    __syncthreads();
    for (int s = 1; s < 256; s <<= 1) {
      int v = (tid >= s) ? sd[tid - s] : 0;
      __syncthreads();
      sd[tid] += v;
      __syncthreads();
    }
    if (f) perm[e * NTOK + base + sd[tid] - 1] = tok;
    int tot = sd[255];
    __syncthreads();
    if (tid == 0) base += tot;
    __syncthreads();
  }
  if (tid == 0) cnt[e] = base;
}

__global__ void cbase_k(const int* __restrict__ cnt, int* __restrict__ cbase) {
  if (threadIdx.x == 0) {
    int b = 0;
    for (int e = 0; e < NEXP; ++e) { cbase[e] = b; b += cnt[e]; }
  }
}

__global__ void f2b_k(const float* __restrict__ src, u16* __restrict__ dst, long n) {
  long i = (long)blockIdx.x * 256 + threadIdx.x;
  if (i < n) dst[i] = f2bf(src[i]);
}

__global__ void f2bsplit_k(const float* __restrict__ src, u16* __restrict__ dh,
                           u16* __restrict__ dl, long n) {
  long i = (long)blockIdx.x * 256 + threadIdx.x;
  if (i < n) { u16 h, l; split2(src[i], h, l); dh[i] = h; dl[i] = l; }
}

extern "C" void kernel_launch(void* const* d_in, const int* in_sizes, int n_in,
                              void* d_out, int out_size, void* d_ws, size_t ws_size,
                              hipStream_t stream) {
  (void)in_sizes; (void)n_in; (void)out_size; (void)ws_size;
  const float* x_in  = (const float*)d_in[0];
  const float* ln1_g = (const float*)d_in[4];
  const float* ln1_b = (const float*)d_in[5];
  const float* w_qkv = (const float*)d_in[6];
  const float* w_out = (const float*)d_in[7];
  const float* gatew = (const float*)d_in[8];
  const float* eg    = (const float*)d_in[9];
  const float* eu    = (const float*)d_in[10];
  const float* ed    = (const float*)d_in[11];
  const float* sg    = (const float*)d_in[12];
  const float* su    = (const float*)d_in[13];
  const float* sd    = (const float*)d_in[14];
  const float* ln2_g = (const float*)d_in[15];
  const float* ln2_b = (const float*)d_in[16];

  float* xc = (float*)d_out;
  char* W = (char*)d_ws;
  size_t off = 0;
  auto alloc = [&](size_t bytes) {
    size_t o = off; off = (off + bytes + 255) & ~(size_t)255; return o;
  };
  // ---- persistent region (~14.3 MB) ----
  size_t o_cos  = alloc((size_t)S_LEN * HDIM * 4);
  size_t o_sin  = alloc((size_t)S_LEN * HDIM * 4);
  size_t o_xnh  = alloc((size_t)NTOK * DM * 2);
  size_t o_xnl  = alloc((size_t)NTOK * DM * 2);
  size_t o_comb = alloc((size_t)NTOK * 4 * 4);
  size_t o_mask = alloc((size_t)NTOK * 4);
  size_t o_perm = alloc((size_t)NEXP * NTOK * 4);
  size_t o_cnt  = alloc(256);
  size_t o_cb   = alloc(256);
  // ---- region A (union, 103.8 MB) ----
  const size_t EGU_B = (size_t)NEXP * FF2 * DM * 2;
  const size_t SGU_B = (size_t)FF2 * DM * 2;
  const size_t SD_B  = (size_t)DM * FF * 2;
  const size_t A_BYTES = 2 * EGU_B + 2 * SGU_B + 2 * SD_B;
  size_t oA = alloc(A_BYTES);
  // attention view of A
  size_t o_qkv = oA;
  size_t o_qph = oA + (size_t)NTOK * 3 * DM * 4;
  size_t o_qpl = o_qph + (size_t)NBH * S_LEN * HDP * 2;
  size_t o_kph = o_qpl + (size_t)NBH * S_LEN * HDP * 2;
  size_t o_kpl = o_kph + (size_t)NBH * S_LEN * HDP * 2;
  size_t o_vth = o_kpl + (size_t)NBH * S_LEN * HDP * 2;
  size_t o_vtl = o_vth + (size_t)NBH * HDP * S_LEN * 2;
  size_t o_omh = o_vtl + (size_t)NBH * HDP * S_LEN * 2;
  size_t o_oml = o_omh + (size_t)NTOK * DM * 2;
  // moe view of A
  size_t o_eguh = oA;
  size_t o_egul = oA + EGU_B;
  size_t o_sguh = oA + 2 * EGU_B;
  size_t o_sgul = o_sguh + SGU_B;
  size_t o_sdh  = o_sgul + SGU_B;
  size_t o_sdl  = o_sdh + SD_B;
  size_t o_edh  = oA;
  size_t o_edl  = oA + (size_t)NEXP * DM * FF * 2;
  // ---- region H (union, 100.7 MB) ----
  const size_t H_BYTES = (size_t)2 * HBROWS * FF * 2;
  size_t oH = alloc(H_BYTES);
  size_t o_wqh = oH;
  size_t o_wql = o_wqh + (size_t)3 * DM * DM * 2;
  size_t o_woh = o_wql + (size_t)3 * DM * DM * 2;
  size_t o_wol = o_woh + (size_t)DM * DM * 2;
  size_t o_hbh = oH;
  size_t o_hbl = oH + (size_t)HBROWS * FF * 2;

  float* cosT = (float*)(W + o_cos);
  float* sinT = (float*)(W + o_sin);
  u16*   xnh  = (u16*)(W + o_xnh);
  u16*   xnl  = (u16*)(W + o_xnl);
  float* comb = (float*)(W + o_comb);
  int* maskb  = (int*)(W + o_mask);
  int* permb  = (int*)(W + o_perm);
  int* cntb   = (int*)(W + o_cnt);
  int* cbaseb = (int*)(W + o_cb);
  float* qkv  = (float*)(W + o_qkv);
  u16 *qph = (u16*)(W + o_qph), *qpl = (u16*)(W + o_qpl);
  u16 *kph = (u16*)(W + o_kph), *kpl = (u16*)(W + o_kpl);
  u16 *vth = (u16*)(W + o_vth), *vtl = (u16*)(W + o_vtl);
  u16 *omh = (u16*)(W + o_omh), *oml = (u16*)(W + o_oml);
  u16 *eguh = (u16*)(W + o_eguh), *egul = (u16*)(W + o_egul);
  u16 *sguh = (u16*)(W + o_sguh), *sgul = (u16*)(W + o_sgul);
  u16 *sdh = (u16*)(W + o_sdh), *sdl = (u16*)(W + o_sdl);
  u16 *edh = (u16*)(W + o_edh), *edl = (u16*)(W + o_edl);
  u16 *wqh = (u16*)(W + o_wqh), *wql = (u16*)(W + o_wql);
  u16 *woh = (u16*)(W + o_woh), *wol = (u16*)(W + o_wol);
  u16 *hbh = (u16*)(W + o_hbh), *hbl = (u16*)(W + o_hbl);

  const long ND = (long)NTOK * DM;
  const int gND = (int)((ND + 255) / 256);

  hipMemcpyAsync(xc, x_in, (size_t)ND * 4, hipMemcpyDeviceToDevice, stream);
  rope_tables_k<<<S_LEN, HDIM, 0, stream>>>(cosT, sinT);

  dim3 tb(32, 8, 1);
  for (int l = 0; l < 2; ++l) {
    const float* wqkv_l = w_qkv + (size_t)l * DM * 3 * DM;
    const float* wout_l = w_out + (size_t)l * DM * DM;
    const float* gw_l   = gatew + (size_t)l * DM * 4;
    const float* eg_l = eg + (size_t)l * NEXP * DM * FF;
    const float* eu_l = eu + (size_t)l * NEXP * DM * FF;
    const float* ed_l = ed + (size_t)l * NEXP * FF * DM;
    const float* sg_l = sg + (size_t)l * DM * FF;
    const float* su_l = su + (size_t)l * DM * FF;
    const float* sd_l = sd + (size_t)l * FF * DM;

    // attention weights into region H (hb is dead here)
    wconv_t<<<dim3(3 * DM / 32, DM / 32, 1), tb, 0, stream>>>(wqkv_l, wqh, wql, DM, 3 * DM, -1, 0, 0);
    wconv_t<<<dim3(DM / 32, DM / 32, 1), tb, 0, stream>>>(wout_l, woh, wol, DM, DM, -1, 0, 0);

    // --- attention (fp32-equivalent via bf16x3 + flash) ---
    ln_k<<<NTOK, 256, 0, stream>>>(xc, ln1_g + l * DM, ln1_b + l * DM, nullptr, xnh, xnl);
    gemm3_nt<0><<<dim3(NTOK >> 7, 3 * DM >> 7, 1), 256, 0, stream>>>(
        xnh, xnl, wqh, wql, qkv, NTOK, 3 * DM, DM, DM, DM, 0, 0, 0, 1, nullptr, nullptr);
    rope_apply_k<<<NTOK, 256, 0, stream>>>(qkv, cosT, sinT, qph, qpl, kph, kpl);
    v_transpose_k<<<dim3(S_LEN / 32, HDP / 32, NBH), tb, 0, stream>>>(qkv, vth, vtl);
    fattn_k<<<dim3(NBH, S_LEN / 64), dim3(256), 0, stream>>>(
        qph, qpl, kph, kpl, vth, vtl, omh, oml, 0.10206207261596575f);
    gemm3_nt<3><<<dim3(NTOK >> 7, DM >> 7, 2), 256, 0, stream>>>(
        omh, oml, woh, wol, xc, NTOK, DM, DM, DM, DM, 0, 0, 0, 2, nullptr, nullptr);

    // --- router + deterministic expert compaction (CSR) ---
    router_k<<<NTOK / 4, 256, 0, stream>>>(xc, gw_l, comb, maskb);
    scan_k<<<NEXP, 256, 0, stream>>>(maskb, permb, cntb);
    cbase_k<<<1, 64, 0, stream>>>(cntb, cbaseb);

    if (l == 0) {
      wconv_t<<<dim3(FF / 32, DM / 32, 1), tb, 0, stream>>>(sg_l, sguh, sgul, DM, FF, 0, 0, 0);
      wconv_t<<<dim3(FF / 32, DM / 32, 1), tb, 0, stream>>>(su_l, sguh, sgul, DM, FF, 1, 0, 0);
      wconv_t<<<dim3(DM / 32, FF / 32, 1), tb, 0, stream>>>(sd_l, sdh, sdl, FF, DM, -1, 0, 0);
      wconv_t<<<dim3(FF / 32, DM / 32, NEXP), tb, 0, stream>>>(
          eg_l, eguh, egul, DM, FF, 0, (long)DM * FF, (long)FF2 * DM);
      wconv_t<<<dim3(FF / 32, DM / 32, NEXP), tb, 0, stream>>>(
          eu_l, eguh, egul, DM, FF, 1, (long)DM * FF, (long)FF2 * DM);

      f2bsplit_k<<<gND, 256, 0, stream>>>(xc, xnh, xnl, ND);
      // shared expert: fused gu+silu -> hb[0..NTOK), down atomic into xc
      gemm3_nt<5><<<dim3(NTOK >> 7, FF2 >> 7, 1), 256, 0, stream>>>(
          xnh, xnl, sguh, sgul, nullptr, NTOK, FF2, DM, DM, DM, 0, 0, 0, 1, hbh, hbl);
      gemm3_nt<3><<<dim3(NTOK >> 7, DM >> 7, 4), 256, 0, stream>>>(
          hbh, hbl, sdh, sdl, xc, NTOK, DM, FF, FF, FF, 0, 0, 0, 4, nullptr, nullptr);
      // all 4 routed experts batched (z = expert)
      gemm3i_nt<5><<<dim3(NTOK >> 7, FF2 >> 7, NEXP), 256, 0, stream>>>(
          xnh, xnl, eguh, egul, nullptr, FF2, DM, DM, DM, FF2,
          permb, cntb, cbaseb, 1, (long)FF2 * DM, hbh, hbl, comb);
      wconv_t<<<dim3(DM / 32, FF / 32, NEXP), tb, 0, stream>>>(
          ed_l, edh, edl, FF, DM, -1, (long)FF * DM, (long)DM * FF);
      gemm3i_nt<1><<<dim3(NTOK >> 7, DM >> 7, NEXP * 4), 256, 0, stream>>>(
          hbh, hbl, edh, edl, xc, DM, FF, FF, FF, DM,
          permb, cntb, cbaseb, 4, (long)DM * FF, nullptr, nullptr, nullptr);
    } else {
      // layer-1: plain bf16 path -> convert hi only (skip lo writes)
      wconv_t<<<dim3(FF / 32, DM / 32, 1), tb, 0, stream>>>(sg_l, sguh, nullptr, DM, FF, 0, 0, 0);
      wconv_t<<<dim3(FF / 32, DM / 32, 1), tb, 0, stream>>>(su_l, sguh, nullptr, DM, FF, 1, 0, 0);
      wconv_t<<<dim3(DM / 32, FF / 32, 1), tb, 0, stream>>>(sd_l, sdh, nullptr, FF, DM, -1, 0, 0);
      wconv_t<<<dim3(FF / 32, DM / 32, NEXP), tb, 0, stream>>>(
          eg_l, eguh, nullptr, DM, FF, 0, (long)DM * FF, (long)FF2 * DM);
      wconv_t<<<dim3(FF / 32, DM / 32, NEXP), tb, 0, stream>>>(
          eu_l, eguh, nullptr, DM, FF, 1, (long)DM * FF, (long)FF2 * DM);

      f2b_k<<<gND, 256, 0, stream>>>(xc, xnh, ND);
      gemm_nt<5><<<dim3(NTOK >> 7, FF2 >> 7, 1), 256, 0, stream>>>(
          xnh, sguh, nullptr, NTOK, FF2, DM, DM, DM, 0, 0, 0, 1, hbh);
      gemm_nt<3><<<dim3(NTOK >> 7, DM >> 7, 4), 256, 0, stream>>>(
          hbh, sdh, xc, NTOK, DM, FF, FF, FF, 0, 0, 0, 4, nullptr);
      gemmi_nt<5><<<dim3(NTOK >> 7, FF2 >> 7, NEXP), 256, 0, stream>>>(
          xnh, eguh, nullptr, FF2, DM, DM, DM, FF2,
          permb, cntb, cbaseb, 1, (long)FF2 * DM, hbh, comb);
      wconv_t<<<dim3(DM / 32, FF / 32, NEXP), tb, 0, stream>>>(
          ed_l, edh, nullptr, FF, DM, -1, (long)FF * DM, (long)DM * FF);
      gemmi_nt<3><<<dim3(NTOK >> 7, DM >> 7, NEXP * 4), 256, 0, stream>>>(
          hbh, edh, xc, DM, FF, FF, FF, DM,
          permb, cntb, cbaseb, 4, (long)DM * FF, nullptr, nullptr);
    }
    ln_k<<<NTOK, 256, 0, stream>>>(xc, ln2_g + l * DM, ln2_b + l * DM, xc, nullptr, nullptr);
  }
}

// Round 12
// 1889.293 us; speedup vs baseline: 1.1961x; 1.1961x over previous
//
#include <hip/hip_runtime.h>
#include <stdint.h>

#define S_LEN 2048
#define DM    768
#define NHEAD 8
#define HDIM  96
#define HDP   128
#define FF    3072
#define FF2   6144
#define NEXP  4
#define NTOK  4096
#define NBH   16
#define HBROWS (2 * NTOK)

typedef unsigned short u16;
typedef short bf16x8 __attribute__((ext_vector_type(8)));
typedef float f32x4 __attribute__((ext_vector_type(4)));
typedef __attribute__((address_space(1))) void* gptr_t;
typedef __attribute__((address_space(3))) void* lptr_t;

__device__ __forceinline__ u16 f2bf(float f) {
  union { float f; uint32_t u; } v; v.f = f;
  uint32_t r = v.u + 0x7FFFu + ((v.u >> 16) & 1u);
  return (u16)(r >> 16);
}
__device__ __forceinline__ float bf2f(u16 h) {
  union { uint32_t u; float f; } v; v.u = ((uint32_t)h) << 16;
  return v.f;
}
__device__ __forceinline__ void split2(float f, u16& hi, u16& lo) {
  u16 h = f2bf(f);
  lo = f2bf(f - bf2f(h));
  hi = h;
}
__device__ __forceinline__ float siluf(float g) {
  return g / (1.0f + expf(-g));
}
__device__ __forceinline__ void gload16(const void* g, void* l) {
  __builtin_amdgcn_global_load_lds((gptr_t)(void*)g, (lptr_t)l, 16, 0, 0);
}
// GEMM-tile LDS swizzle (64B rows): chunk bits 4-5 XOR row bits 1-2 (byte 7-8).
__device__ __forceinline__ int swz(int byte) {
  return byte ^ (((byte >> 7) & 3) << 4);
}

// ---------------------------------------------------------------------------
// Plain NT GEMM, 2-phase double-buffered. C[M,N] = A[M,K] @ B[N,K]^T.
// Grid: (N/128, M/128, batch*kspl)  [round-10 proven orientation].
// MODE: 0 f32, 2 bf16, 3 atomic f32, 5 fused gate/up silu -> hb bf16.
// ---------------------------------------------------------------------------
template<int MODE>
__global__ __launch_bounds__(256) void gemm_nt(
    const u16* __restrict__ A, const u16* __restrict__ B, void* __restrict__ Cv,
    int M, int N, int K, int lda, int ldb, long sA, long sB, long sC, int kspl,
    u16* __restrict__ hb)
{
  __shared__ u16 As[2][128 * 32];
  __shared__ u16 Bs[2][128 * 32];
  const int z = blockIdx.z;
  const int bh = z / kspl;
  const int kc = z - bh * kspl;
  const u16* Az = A + (long)bh * sA;
  const u16* Bz = B + (long)bh * sB;
  const int brow = blockIdx.y << 7;
  const int bcol = blockIdx.x << 7;
  const int tid = threadIdx.x;
  const int wid = tid >> 6;
  const int lane = tid & 63;
  const int wr = (wid >> 1) << 6;
  const int wc = (wid & 1) << 6;

  f32x4 acc[4][4] = {};
  const int a0 = (wid << 11) + (lane << 4);

  auto stage = [&](int buf, int k0) {
#pragma unroll
    for (int c = 0; c < 2; ++c) {
      int ab = a0 + (c << 10);
      int lb = swz(ab);
      int row = ab >> 6;
      int kcol = (lb & 63) >> 1;
      int ld = (wid << 11) + (c << 10);
      gload16(Az + (long)(brow + row) * lda + (k0 + kcol), (char*)As[buf] + ld);
      gload16(Bz + (long)(bcol + row) * ldb + (k0 + kcol), (char*)Bs[buf] + ld);
    }
  };

  const int kt = K / kspl;
  const int kbeg = kc * kt;
  const int nt = kt >> 5;
  stage(0, kbeg);
  __syncthreads();
  for (int t = 0; t < nt; ++t) {
    const int cur = t & 1;
    if (t + 1 < nt) stage(cur ^ 1, kbeg + ((t + 1) << 5));
    bf16x8 af[4], bfr[4];
    const int lr = lane & 15;
    const int lk = (lane >> 4) << 4;
#pragma unroll
    for (int m = 0; m < 4; ++m)
      af[m] = *(const bf16x8*)((const char*)As[cur] + swz((((wr + m * 16 + lr) << 6) + lk)));
#pragma unroll
    for (int n = 0; n < 4; ++n)
      bfr[n] = *(const bf16x8*)((const char*)Bs[cur] + swz((((wc + n * 16 + lr) << 6) + lk)));
#pragma unroll
    for (int m = 0; m < 4; ++m)
#pragma unroll
      for (int n = 0; n < 4; ++n)
        acc[m][n] = __builtin_amdgcn_mfma_f32_16x16x32_bf16(af[m], bfr[n], acc[m][n], 0, 0, 0);
    if (t + 1 < nt) __syncthreads();
  }

  const int crow0 = brow + wr + ((lane >> 4) << 2);
  const int ccol0 = bcol + wc + (lane & 15);
  const long cbase = (long)bh * sC;
  if constexpr (MODE == 5) {
    const int pbase = (bcol + wc) >> 5;
#pragma unroll
    for (int m = 0; m < 4; ++m)
#pragma unroll
      for (int np = 0; np < 2; ++np)
#pragma unroll
        for (int j = 0; j < 4; ++j) {
          int r = crow0 + m * 16 + j;
          float g = acc[m][2 * np][j], u = acc[m][2 * np + 1][j];
          int hcol = ((pbase + np) << 4) + (lane & 15);
          hb[(long)r * FF + hcol] = f2bf(siluf(g) * u);
        }
  } else {
#pragma unroll
    for (int m = 0; m < 4; ++m)
#pragma unroll
      for (int n = 0; n < 4; ++n)
#pragma unroll
        for (int j = 0; j < 4; ++j) {
          long idx = cbase + (long)(crow0 + m * 16 + j) * N + (ccol0 + n * 16);
          float v = acc[m][n][j];
          if constexpr (MODE == 2) ((u16*)Cv)[idx] = f2bf(v);
          else if constexpr (MODE == 3) unsafeAtomicAdd((float*)Cv + idx, v);
          else ((float*)Cv)[idx] = v;
        }
  }
}

// ---------------------------------------------------------------------------
// Split (bf16x3) NT GEMM, dense. MODE: 0 f32, 3 atomic f32, 5 fused gu silu.
// Grid: (N/128, M/128, batch*kspl).
// ---------------------------------------------------------------------------
template<int MODE>
__global__ __launch_bounds__(256) void gemm3_nt(
    const u16* __restrict__ Ah, const u16* __restrict__ Al,
    const u16* __restrict__ Bh, const u16* __restrict__ Bl,
    float* __restrict__ C,
    int M, int N, int K, int lda, int ldb, long sA, long sB, long sC, int kspl,
    u16* __restrict__ hbh, u16* __restrict__ hbl)
{
  __shared__ u16 Ash[2][128 * 32], Asl[2][128 * 32];
  __shared__ u16 Bsh[2][128 * 32], Bsl[2][128 * 32];
  const int z = blockIdx.z;
  const int bh = z / kspl;
  const int kc = z - bh * kspl;
  const u16* Azh = Ah + (long)bh * sA;
  const u16* Azl = Al + (long)bh * sA;
  const u16* Bzh = Bh + (long)bh * sB;
  const u16* Bzl = Bl + (long)bh * sB;
  const int brow = blockIdx.y << 7;
  const int bcol = blockIdx.x << 7;
  const int tid = threadIdx.x;
  const int wid = tid >> 6;
  const int lane = tid & 63;
  const int wr = (wid >> 1) << 6;
  const int wc = (wid & 1) << 6;

  f32x4 acc[4][4] = {};
  const int a0 = (wid << 11) + (lane << 4);

  auto stage = [&](int buf, int k0) {
#pragma unroll
    for (int c = 0; c < 2; ++c) {
      int ab = a0 + (c << 10);
      int lb = swz(ab);
      int row = ab >> 6;
      int kcol = (lb & 63) >> 1;
      long ao = (long)(brow + row) * lda + (k0 + kcol);
      long bo = (long)(bcol + row) * ldb + (k0 + kcol);
      int ld = (wid << 11) + (c << 10);
      gload16(Azh + ao, (char*)Ash[buf] + ld);
      gload16(Azl + ao, (char*)Asl[buf] + ld);
      gload16(Bzh + bo, (char*)Bsh[buf] + ld);
      gload16(Bzl + bo, (char*)Bsl[buf] + ld);
    }
  };

  const int kt = K / kspl;
  const int kbeg = kc * kt;
  const int nt = kt >> 5;
  stage(0, kbeg);
  __syncthreads();
  for (int t = 0; t < nt; ++t) {
    const int cur = t & 1;
    if (t + 1 < nt) stage(cur ^ 1, kbeg + ((t + 1) << 5));
    const int lr = lane & 15;
    const int lk = (lane >> 4) << 4;
    bf16x8 ah[4], al[4], bh_[4], bl[4];
#pragma unroll
    for (int m = 0; m < 4; ++m) {
      int off = swz(((wr + m * 16 + lr) << 6) + lk);
      ah[m] = *(const bf16x8*)((const char*)Ash[cur] + off);
      al[m] = *(const bf16x8*)((const char*)Asl[cur] + off);
    }
#pragma unroll
    for (int n = 0; n < 4; ++n) {
      int off = swz(((wc + n * 16 + lr) << 6) + lk);
      bh_[n] = *(const bf16x8*)((const char*)Bsh[cur] + off);
      bl[n] = *(const bf16x8*)((const char*)Bsl[cur] + off);
    }
#pragma unroll
    for (int m = 0; m < 4; ++m)
#pragma unroll
      for (int n = 0; n < 4; ++n) {
        acc[m][n] = __builtin_amdgcn_mfma_f32_16x16x32_bf16(al[m], bh_[n], acc[m][n], 0, 0, 0);
        acc[m][n] = __builtin_amdgcn_mfma_f32_16x16x32_bf16(ah[m], bl[n], acc[m][n], 0, 0, 0);
        acc[m][n] = __builtin_amdgcn_mfma_f32_16x16x32_bf16(ah[m], bh_[n], acc[m][n], 0, 0, 0);
      }
    if (t + 1 < nt) __syncthreads();
  }

  const int crow0 = brow + wr + ((lane >> 4) << 2);
  const int ccol0 = bcol + wc + (lane & 15);
  const long cbase = (long)bh * sC;
  if constexpr (MODE == 5) {
    const int pbase = (bcol + wc) >> 5;
#pragma unroll
    for (int m = 0; m < 4; ++m)
#pragma unroll
      for (int np = 0; np < 2; ++np)
#pragma unroll
        for (int j = 0; j < 4; ++j) {
          int r = crow0 + m * 16 + j;
          float g = acc[m][2 * np][j], u = acc[m][2 * np + 1][j];
          float h = siluf(g) * u;
          int hcol = ((pbase + np) << 4) + (lane & 15);
          u16 hh, ll; split2(h, hh, ll);
          hbh[(long)r * FF + hcol] = hh;
          hbl[(long)r * FF + hcol] = ll;
        }
  } else {
#pragma unroll
    for (int m = 0; m < 4; ++m)
#pragma unroll
      for (int n = 0; n < 4; ++n)
#pragma unroll
        for (int j = 0; j < 4; ++j) {
          long idx = cbase + (long)(crow0 + m * 16 + j) * N + (ccol0 + n * 16);
          if constexpr (MODE == 3) unsafeAtomicAdd(&C[idx], acc[m][n][j]);
          else C[idx] = acc[m][n][j];
        }
  }
}

// ---------------------------------------------------------------------------
// Batched indirect split GEMM over experts (blockIdx.z = e*kspl+kc).
// Grid: (N/128, Mmax/128, NEXP*kspl).
// MODE 5: gather-A via perm[e], fused gu silu * comb -> hb rows cbase[e]+r.
// MODE 1: compact-A rows cbase[e]+r (clamped), scatter-atomic f32.
// ---------------------------------------------------------------------------
template<int MODE>
__global__ __launch_bounds__(256) void gemm3i_nt(
    const u16* __restrict__ Ah, const u16* __restrict__ Al,
    const u16* __restrict__ Bh, const u16* __restrict__ Bl,
    float* __restrict__ C, int N, int K, int lda, int ldb, int ldc,
    const int* __restrict__ perm, const int* __restrict__ cnt,
    const int* __restrict__ cbase, int kspl, long wstride,
    u16* __restrict__ hbh, u16* __restrict__ hbl, const float* __restrict__ comb)
{
  const int z = blockIdx.z;
  const int e = z / kspl;
  const int kc = z - e * kspl;
  const int cn = cnt[e];
  const int brow = blockIdx.y << 7;
  if (brow >= cn) return;
  const int cb = cbase[e];
  const int* pe = perm + e * NTOK;
  const u16* Bhe = Bh + (long)e * wstride;
  const u16* Ble = Bl + (long)e * wstride;
  __shared__ u16 Ash[2][128 * 32], Asl[2][128 * 32];
  __shared__ u16 Bsh[2][128 * 32], Bsl[2][128 * 32];
  const int bcol = blockIdx.x << 7;
  const int tid = threadIdx.x;
  const int wid = tid >> 6;
  const int lane = tid & 63;
  const int wr = (wid >> 1) << 6;
  const int wc = (wid & 1) << 6;

  f32x4 acc[4][4] = {};
  const int a0 = (wid << 11) + (lane << 4);

  int arow[2];
#pragma unroll
  for (int c = 0; c < 2; ++c) {
    int ab = a0 + (c << 10);
    int row = ab >> 6;
    int g = brow + row;
    if constexpr (MODE == 5) {
      arow[c] = (g < cn) ? pe[g] : pe[brow];
    } else {
      arow[c] = cb + ((g < cn) ? g : (cn - 1));
    }
  }

  auto stage = [&](int buf, int k0) {
#pragma unroll
    for (int c = 0; c < 2; ++c) {
      int ab = a0 + (c << 10);
      int lb = swz(ab);
      int row = ab >> 6;
      int kcol = (lb & 63) >> 1;
      int ld = (wid << 11) + (c << 10);
      gload16(Ah + (long)arow[c] * lda + (k0 + kcol), (char*)Ash[buf] + ld);
      gload16(Al + (long)arow[c] * lda + (k0 + kcol), (char*)Asl[buf] + ld);
      long bo = (long)(bcol + row) * ldb + (k0 + kcol);
      gload16(Bhe + bo, (char*)Bsh[buf] + ld);
      gload16(Ble + bo, (char*)Bsl[buf] + ld);
    }
  };

  const int kt = K / kspl;
  const int kbeg = kc * kt;
  const int nt = kt >> 5;
  stage(0, kbeg);
  __syncthreads();
  for (int t = 0; t < nt; ++t) {
    const int cur = t & 1;
    if (t + 1 < nt) stage(cur ^ 1, kbeg + ((t + 1) << 5));
    const int lr = lane & 15;
    const int lk = (lane >> 4) << 4;
    bf16x8 ah[4], al[4], bh_[4], bl[4];
#pragma unroll
    for (int m = 0; m < 4; ++m) {
      int off = swz(((wr + m * 16 + lr) << 6) + lk);
      ah[m] = *(const bf16x8*)((const char*)Ash[cur] + off);
      al[m] = *(const bf16x8*)((const char*)Asl[cur] + off);
    }
#pragma unroll
    for (int n = 0; n < 4; ++n) {
      int off = swz(((wc + n * 16 + lr) << 6) + lk);
      bh_[n] = *(const bf16x8*)((const char*)Bsh[cur] + off);
      bl[n] = *(const bf16x8*)((const char*)Bsl[cur] + off);
    }
#pragma unroll
    for (int m = 0; m < 4; ++m)
#pragma unroll
      for (int n = 0; n < 4; ++n) {
        acc[m][n] = __builtin_amdgcn_mfma_f32_16x16x32_bf16(al[m], bh_[n], acc[m][n], 0, 0, 0);
        acc[m][n] = __builtin_amdgcn_mfma_f32_16x16x32_bf16(ah[m], bl[n], acc[m][n], 0, 0, 0);
        acc[m][n] = __builtin_amdgcn_mfma_f32_16x16x32_bf16(ah[m], bh_[n], acc[m][n], 0, 0, 0);
      }
    if (t + 1 < nt) __syncthreads();
  }

  const int crow0 = brow + wr + ((lane >> 4) << 2);
  const int ccol0 = bcol + wc + (lane & 15);
  if constexpr (MODE == 5) {
    const int pbase = (bcol + wc) >> 5;
#pragma unroll
    for (int m = 0; m < 4; ++m)
#pragma unroll
      for (int j = 0; j < 4; ++j) {
        int r = crow0 + m * 16 + j;
        if (r < cn) {
          float w = comb[pe[r] * 4 + e];
#pragma unroll
          for (int np = 0; np < 2; ++np) {
            float g = acc[m][2 * np][j], u = acc[m][2 * np + 1][j];
            float h = siluf(g) * u * w;
            int hcol = ((pbase + np) << 4) + (lane & 15);
            u16 hh, ll; split2(h, hh, ll);
            hbh[(long)(cb + r) * FF + hcol] = hh;
            hbl[(long)(cb + r) * FF + hcol] = ll;
          }
        }
      }
  } else {
#pragma unroll
    for (int m = 0; m < 4; ++m)
#pragma unroll
      for (int n = 0; n < 4; ++n)
#pragma unroll
        for (int j = 0; j < 4; ++j) {
          int r = crow0 + m * 16 + j;
          if (r < cn) {
            int col = ccol0 + n * 16;
            unsafeAtomicAdd(&C[(long)pe[r] * ldc + col], acc[m][n][j]);
          }
        }
  }
}

// ---------------------------------------------------------------------------
// Batched indirect plain bf16 GEMM over experts (layer-1).
// MODE 5: gather-A, fused gu -> hb rows cbase[e]+r. MODE 3: compact-A, scatter.
// ---------------------------------------------------------------------------
template<int MODE>
__global__ __launch_bounds__(256) void gemmi_nt(
    const u16* __restrict__ A, const u16* __restrict__ B, void* __restrict__ Cv,
    int N, int K, int lda, int ldb, int ldc,
    const int* __restrict__ perm, const int* __restrict__ cnt,
    const int* __restrict__ cbase, int kspl, long wstride,
    u16* __restrict__ hb, const float* __restrict__ comb)
{
  const int z = blockIdx.z;
  const int e = z / kspl;
  const int kc = z - e * kspl;
  const int cn = cnt[e];
  const int brow = blockIdx.y << 7;
  if (brow >= cn) return;
  const int cb = cbase[e];
  const int* pe = perm + e * NTOK;
  const u16* Be = B + (long)e * wstride;
  __shared__ u16 As[2][128 * 32];
  __shared__ u16 Bs[2][128 * 32];
  const int bcol = blockIdx.x << 7;
  const int tid = threadIdx.x;
  const int wid = tid >> 6;
  const int lane = tid & 63;
  const int wr = (wid >> 1) << 6;
  const int wc = (wid & 1) << 6;

  f32x4 acc[4][4] = {};
  const int a0 = (wid << 11) + (lane << 4);

  int arow[2];
#pragma unroll
  for (int c = 0; c < 2; ++c) {
    int ab = a0 + (c << 10);
    int row = ab >> 6;
    int g = brow + row;
    if constexpr (MODE == 5) {
      arow[c] = (g < cn) ? pe[g] : pe[brow];
    } else {
      arow[c] = cb + ((g < cn) ? g : (cn - 1));
    }
  }

  auto stage = [&](int buf, int k0) {
#pragma unroll
    for (int c = 0; c < 2; ++c) {
      int ab = a0 + (c << 10);
      int lb = swz(ab);
      int row = ab >> 6;
      int kcol = (lb & 63) >> 1;
      int ld = (wid << 11) + (c << 10);
      gload16(A + (long)arow[c] * lda + (k0 + kcol), (char*)As[buf] + ld);
      gload16(Be + (long)(bcol + row) * ldb + (k0 + kcol), (char*)Bs[buf] + ld);
    }
  };

  const int kt = K / kspl;
  const int kbeg = kc * kt;
  const int nt = kt >> 5;
  stage(0, kbeg);
  __syncthreads();
  for (int t = 0; t < nt; ++t) {
    const int cur = t & 1;
    if (t + 1 < nt) stage(cur ^ 1, kbeg + ((t + 1) << 5));
    bf16x8 af[4], bfr[4];
    const int lr = lane & 15;
    const int lk = (lane >> 4) << 4;
#pragma unroll
    for (int m = 0; m < 4; ++m)
      af[m] = *(const bf16x8*)((const char*)As[cur] + swz((((wr + m * 16 + lr) << 6) + lk)));
#pragma unroll
    for (int n = 0; n < 4; ++n)
      bfr[n] = *(const bf16x8*)((const char*)Bs[cur] + swz((((wc + n * 16 + lr) << 6) + lk)));
#pragma unroll
    for (int m = 0; m < 4; ++m)
#pragma unroll
      for (int n = 0; n < 4; ++n)
        acc[m][n] = __builtin_amdgcn_mfma_f32_16x16x32_bf16(af[m], bfr[n], acc[m][n], 0, 0, 0);
    if (t + 1 < nt) __syncthreads();
  }

  const int crow0 = brow + wr + ((lane >> 4) << 2);
  const int ccol0 = bcol + wc + (lane & 15);
  if constexpr (MODE == 5) {
    const int pbase = (bcol + wc) >> 5;
#pragma unroll
    for (int m = 0; m < 4; ++m)
#pragma unroll
      for (int j = 0; j < 4; ++j) {
        int r = crow0 + m * 16 + j;
        if (r < cn) {
          float w = comb[pe[r] * 4 + e];
#pragma unroll
          for (int np = 0; np < 2; ++np) {
            float g = acc[m][2 * np][j], u = acc[m][2 * np + 1][j];
            int hcol = ((pbase + np) << 4) + (lane & 15);
            hb[(long)(cb + r) * FF + hcol] = f2bf(siluf(g) * u * w);
          }
        }
      }
  } else {
#pragma unroll
    for (int m = 0; m < 4; ++m)
#pragma unroll
      for (int n = 0; n < 4; ++n)
#pragma unroll
        for (int j = 0; j < 4; ++j) {
          int r = crow0 + m * 16 + j;
          if (r < cn) {
            int col = ccol0 + n * 16;
            unsafeAtomicAdd((float*)Cv + (long)pe[r] * ldc + col, acc[m][n][j]);
          }
        }
  }
}

// ---------------------------------------------------------------------------
// Fused flash attention. QK computed over exact K=96 (pad cols are zero).
// ---------------------------------------------------------------------------
__global__ __launch_bounds__(256, 2) void fattn_k(
    const u16* __restrict__ qh, const u16* __restrict__ ql,
    const u16* __restrict__ kh, const u16* __restrict__ kl,
    const u16* __restrict__ vth, const u16* __restrict__ vtl,
    u16* __restrict__ omh, u16* __restrict__ oml, float scale)
{
  __shared__ u16 Ksh[64 * 128], Ksl[64 * 128];
  __shared__ u16 Vsh[128 * 64], Vsl[128 * 64];
  const int bh = blockIdx.x;
  const int qt = blockIdx.y;
  const int tid = threadIdx.x, wid = tid >> 6, lane = tid & 63;
  const int lr = lane & 15, lg = lane >> 4;
  const int q0 = qt * 64 + wid * 16;
  const long bhoff = (long)bh * S_LEN * HDP;
  const u16* Qh = qh + bhoff;  const u16* Ql = ql + bhoff;
  const u16* Kgh = kh + bhoff; const u16* Kgl = kl + bhoff;
  const u16* Vgh = vth + bhoff; const u16* Vgl = vtl + bhoff;

  bf16x8 qfh[3], qfl[3];
#pragma unroll
  for (int kk = 0; kk < 3; ++kk) {
    long o = (long)(q0 + lr) * HDP + kk * 32 + lg * 8;
    qfh[kk] = *(const bf16x8*)(Qh + o);
    qfl[kk] = *(const bf16x8*)(Ql + o);
  }

  f32x4 oacc[6] = {};
  float rm[4], rls[4];
#pragma unroll
  for (int j = 0; j < 4; ++j) { rm[j] = -1e30f; rls[j] = 0.f; }

  for (int t = 0; t < S_LEN / 64; ++t) {
    __syncthreads();
#pragma unroll
    for (int c = 0; c < 4; ++c) {
      int off = (tid + (c << 8)) << 4;
      {
        int lb = off ^ ((((off >> 8) & 7)) << 4);
        int row = lb >> 8, colh = (lb & 255) >> 1;
        long src = (long)(t * 64 + row) * HDP + colh;
        gload16(Kgh + src, (char*)Ksh + off);
        gload16(Kgl + src, (char*)Ksl + off);
      }
      {
        int lb = off ^ ((((off >> 7) & 7)) << 4);
        int row = lb >> 7, colh = (lb & 127) >> 1;
        long src = (long)row * S_LEN + t * 64 + colh;
        gload16(Vgh + src, (char*)Vsh + off);
        gload16(Vgl + src, (char*)Vsl + off);
      }
    }
    __syncthreads();

    f32x4 sacc[4] = {};
#pragma unroll
    for (int kk = 0; kk < 3; ++kk) {
      bf16x8 kbh[4], kbl[4];
#pragma unroll
      for (int n = 0; n < 4; ++n) {
        int byte = ((n * 16 + lr) << 8) + (kk << 6) + (lg << 4);
        byte ^= ((byte >> 8) & 7) << 4;
        kbh[n] = *(const bf16x8*)((const char*)Ksh + byte);
        kbl[n] = *(const bf16x8*)((const char*)Ksl + byte);
      }
      __builtin_amdgcn_s_setprio(1);
#pragma unroll
      for (int n = 0; n < 4; ++n) {
        sacc[n] = __builtin_amdgcn_mfma_f32_16x16x32_bf16(qfl[kk], kbh[n], sacc[n], 0, 0, 0);
        sacc[n] = __builtin_amdgcn_mfma_f32_16x16x32_bf16(qfh[kk], kbl[n], sacc[n], 0, 0, 0);
        sacc[n] = __builtin_amdgcn_mfma_f32_16x16x32_bf16(qfh[kk], kbh[n], sacc[n], 0, 0, 0);
      }
      __builtin_amdgcn_s_setprio(0);
    }
    __syncthreads();

#pragma unroll
    for (int j = 0; j < 4; ++j) {
      float mx = fmaxf(fmaxf(sacc[0][j], sacc[1][j]),
                       fmaxf(sacc[2][j], sacc[3][j])) * scale;
      mx = fmaxf(mx, __shfl_xor(mx, 1));
      mx = fmaxf(mx, __shfl_xor(mx, 2));
      mx = fmaxf(mx, __shfl_xor(mx, 4));
      mx = fmaxf(mx, __shfl_xor(mx, 8));
      float mnew = fmaxf(rm[j], mx);
      float corr = __expf(rm[j] - mnew);
      rm[j] = mnew;
      float ps = 0.f;
#pragma unroll
      for (int n = 0; n < 4; ++n) {
        float p = __expf(sacc[n][j] * scale - mnew);
        sacc[n][j] = p; ps += p;
      }
      ps += __shfl_xor(ps, 1); ps += __shfl_xor(ps, 2);
      ps += __shfl_xor(ps, 4); ps += __shfl_xor(ps, 8);
      rls[j] = rls[j] * corr + ps;
#pragma unroll
      for (int n2 = 0; n2 < 6; ++n2) oacc[n2][j] *= corr;
    }

    char* Pwh = (char*)Ksh + (wid << 11);
    char* Pwl = (char*)Ksl + (wid << 11);
#pragma unroll
    for (int n = 0; n < 4; ++n)
#pragma unroll
      for (int j = 0; j < 4; ++j) {
        int row = lg * 4 + j;
        int byte = (row << 7) + ((n * 16 + lr) << 1);
        byte ^= ((byte >> 7) & 7) << 4;
        u16 h, l; split2(sacc[n][j], h, l);
        *(u16*)(Pwh + byte) = h;
        *(u16*)(Pwl + byte) = l;
      }
    bf16x8 pah[2], pal[2];
#pragma unroll
    for (int kk = 0; kk < 2; ++kk) {
      int byte = (lr << 7) + (kk << 6) + (lg << 4);
      byte ^= ((byte >> 7) & 7) << 4;
      pah[kk] = *(const bf16x8*)(Pwh + byte);
      pal[kk] = *(const bf16x8*)(Pwl + byte);
    }

#pragma unroll
    for (int kk = 0; kk < 2; ++kk) {
      bf16x8 vbh[6], vbl[6];
#pragma unroll
      for (int n2 = 0; n2 < 6; ++n2) {
        int byte = ((n2 * 16 + lr) << 7) + (kk << 6) + (lg << 4);
        byte ^= ((byte >> 7) & 7) << 4;
        vbh[n2] = *(const bf16x8*)((const char*)Vsh + byte);
        vbl[n2] = *(const bf16x8*)((const char*)Vsl + byte);
      }
      __builtin_amdgcn_s_setprio(1);
#pragma unroll
      for (int n2 = 0; n2 < 6; ++n2) {
        oacc[n2] = __builtin_amdgcn_mfma_f32_16x16x32_bf16(pal[kk], vbh[n2], oacc[n2], 0, 0, 0);
        oacc[n2] = __builtin_amdgcn_mfma_f32_16x16x32_bf16(pah[kk], vbl[n2], oacc[n2], 0, 0, 0);
        oacc[n2] = __builtin_amdgcn_mfma_f32_16x16x32_bf16(pah[kk], vbh[n2], oacc[n2], 0, 0, 0);
      }
      __builtin_amdgcn_s_setprio(0);
    }
  }

  const int b = bh >> 3, h = bh & 7;
#pragma unroll
  for (int j = 0; j < 4; ++j) {
    float inv = 1.0f / rls[j];
    int q = q0 + lg * 4 + j;
    long base = ((long)(b * S_LEN + q)) * DM + h * HDIM;
#pragma unroll
    for (int n2 = 0; n2 < 6; ++n2) {
      int d = n2 * 16 + lr;
      u16 hh, ll; split2(oacc[n2][j] * inv, hh, ll);
      omh[base + d] = hh; oml[base + d] = ll;
    }
  }
}

// ---------------------------------------------------------------------------
// fp32 [R][C] -> bf16 hi/lo [C][R] transpose+split, z-batched.
// ilv<0: linear rows; ilv in {0,1}: gate/up 16-row interleave. outl optional.
// ---------------------------------------------------------------------------
__global__ void wconv_t(const float* __restrict__ in, u16* __restrict__ outh,
                        u16* __restrict__ outl, int R, int C, int ilv,
                        long inStride, long outStride) {
  __shared__ float tile[32][33];
  long z = blockIdx.z;
  in += z * inStride; outh += z * outStride;
  if (outl) outl += z * outStride;
  int c0 = blockIdx.x << 5, r0 = blockIdx.y << 5;
  int tx = threadIdx.x;
  for (int rr = threadIdx.y; rr < 32; rr += 8)
    tile[rr][tx] = in[(long)(r0 + rr) * C + (c0 + tx)];
  __syncthreads();
  for (int rr = threadIdx.y; rr < 32; rr += 8) {
    u16 h, l; split2(tile[tx][rr], h, l);
    int f = c0 + rr;
    long orow = (ilv < 0) ? f : (((f >> 4) << 5) + (ilv << 4) + (f & 15));
    long o = orow * R + (r0 + tx);
    outh[o] = h;
    if (outl) outl[o] = l;
  }
}

__global__ __launch_bounds__(256) void ln_k(const float* __restrict__ in,
    const float* __restrict__ g, const float* __restrict__ b,
    float* __restrict__ outf, u16* __restrict__ outh, u16* __restrict__ outl) {
  int row = blockIdx.x;
  const float* x = in + (long)row * DM;
  int tid = threadIdx.x;
  float v[3], s = 0.f, ss = 0.f;
#pragma unroll
  for (int i = 0; i < 3; ++i) { v[i] = x[tid + (i << 8)]; s += v[i]; ss += v[i] * v[i]; }
  __shared__ float red[2][4];
  for (int o = 32; o; o >>= 1) { s += __shfl_down(s, o); ss += __shfl_down(ss, o); }
  int wid = tid >> 6, lane = tid & 63;
  if (!lane) { red[0][wid] = s; red[1][wid] = ss; }
  __syncthreads();
  s = red[0][0] + red[0][1] + red[0][2] + red[0][3];
  ss = red[1][0] + red[1][1] + red[1][2] + red[1][3];
  float mean = s * (1.f / DM);
  float var = ss * (1.f / DM) - mean * mean;
  float rs = rsqrtf(var + 1e-5f);
#pragma unroll
  for (int i = 0; i < 3; ++i) {
    int c = tid + (i << 8);
    float y = (v[i] - mean) * rs * g[c] + b[c];
    if (outf) outf[(long)row * DM + c] = y;
    if (outh) { u16 h, l; split2(y, h, l); outh[(long)row * DM + c] = h; outl[(long)row * DM + c] = l; }
  }
}

__global__ void rope_tables_k(float* __restrict__ cosT, float* __restrict__ sinT) {
  int s = blockIdx.x, d = threadIdx.x;
  int xc = s & 15, y = (s >> 4) & 15, t = s >> 8;
  int axis = d / 32, fi = d & 15;
  int coord = axis == 0 ? xc : (axis == 1 ? y : t);
  float inv = powf(10000.0f, -(float)fi / 16.0f);
  float ang = (float)coord * inv;
  cosT[s * HDIM + d] = cosf(ang);
  sinT[s * HDIM + d] = sinf(ang);
}

__global__ __launch_bounds__(256) void rope_apply_k(const float* __restrict__ qkv,
    const float* __restrict__ cosT, const float* __restrict__ sinT,
    u16* __restrict__ qh, u16* __restrict__ ql,
    u16* __restrict__ kh, u16* __restrict__ kl) {
  int bs = blockIdx.x;
  int b = bs >> 11, s = bs & 2047;
  const float* base = qkv + ((long)(b * S_LEN + s) * 3) * DM;
  for (int idx = threadIdx.x; idx < DM; idx += 256) {
    int h = idx / HDIM, d = idx - h * HDIM;
    float c = cosT[s * HDIM + d], sn = sinT[s * HDIM + d];
    int pair = (d < 48) ? idx + 48 : idx - 48;
    float qv = base[idx], kv = base[DM + idx];
    float qr = (d < 48) ? -base[pair] : base[pair];
    float kr = (d < 48) ? -base[DM + pair] : base[DM + pair];
    long o = ((long)(b * NHEAD + h) * S_LEN + s) * HDP + d;
    u16 hh, ll;
    split2(qv * c + qr * sn, hh, ll); qh[o] = hh; ql[o] = ll;
    split2(kv * c + kr * sn, hh, ll); kh[o] = hh; kl[o] = ll;
  }
  int t = threadIdx.x;
  int h = t >> 5, d = HDIM + (t & 31);
  long o = ((long)(b * NHEAD + h) * S_LEN + s) * HDP + d;
  qh[o] = 0; ql[o] = 0; kh[o] = 0; kl[o] = 0;
}

__global__ void v_transpose_k(const float* __restrict__ qkv,
                              u16* __restrict__ vh, u16* __restrict__ vl) {
  __shared__ float tile[32][33];
  int bh = blockIdx.z, b = bh >> 3, h = bh & 7;
  int s0 = blockIdx.x << 5, d0 = blockIdx.y << 5;
  int tx = threadIdx.x;
  for (int r = threadIdx.y; r < 32; r += 8) {
    int s = s0 + r, d = d0 + tx;
    float v = 0.f;
    if (d < HDIM) v = qkv[((long)(b * S_LEN + s) * 3 + 2) * DM + h * HDIM + d];
    tile[r][tx] = v;
  }
  __syncthreads();
  for (int r = threadIdx.y; r < 32; r += 8) {
    int d = d0 + r;
    u16 hh, ll; split2(tile[tx][r], hh, ll);
    long o = ((long)bh * HDP + d) * S_LEN + (s0 + tx);
    vh[o] = hh; vl[o] = ll;
  }
}

// Router: comb[tok][e] + top-2 bitmask per token.
__global__ __launch_bounds__(256) void router_k(const float* __restrict__ x,
    const float* __restrict__ gw, float* __restrict__ comb, int* __restrict__ mask) {
  int tok = blockIdx.x * 4 + (threadIdx.x >> 6);
  int lane = threadIdx.x & 63;
  const float* xr = x + (long)tok * DM;
  float a0 = 0, a1 = 0, a2 = 0, a3 = 0;
  for (int i = lane; i < DM; i += 64) {
    float xv = xr[i];
    const float* g = gw + i * 4;
    a0 += xv * g[0]; a1 += xv * g[1]; a2 += xv * g[2]; a3 += xv * g[3];
  }
  for (int o = 32; o; o >>= 1) {
    a0 += __shfl_down(a0, o); a1 += __shfl_down(a1, o);
    a2 += __shfl_down(a2, o); a3 += __shfl_down(a3, o);
  }
  if (lane == 0) {
    float p[4] = {a0, a1, a2, a3};
    float mx = fmaxf(fmaxf(p[0], p[1]), fmaxf(p[2], p[3]));
    float s = 0.f;
    for (int e = 0; e < 4; ++e) { p[e] = expf(p[e] - mx); s += p[e]; }
    for (int e = 0; e < 4; ++e) p[e] /= s;
    int i1 = 0;
    for (int e = 1; e < 4; ++e) if (p[e] > p[i1]) i1 = e;
    int i2 = -1;
    for (int e = 0; e < 4; ++e) if (e != i1 && (i2 < 0 || p[e] > p[i2])) i2 = e;
    float ssum = p[i1] + p[i2] + 1e-5f;
    float out[4] = {0, 0, 0, 0};
    out[i1] = p[i1] / ssum; out[i2] = p[i2] / ssum;
    for (int e = 0; e < 4; ++e) comb[tok * 4 + e] = out[e];
    mask[tok] = (1 << i1) | (1 << i2);
  }
}

// Deterministic per-expert compaction; one block per expert (grid = NEXP).
__global__ void scan_k(const int* __restrict__ mask, int* __restrict__ perm,
                       int* __restrict__ cnt) {
  __shared__ int sd[256];
  __shared__ int base;
  int tid = threadIdx.x;
  int e = blockIdx.x;
  if (tid == 0) base = 0;
  __syncthreads();
  for (int c = 0; c < NTOK / 256; ++c) {
    int tok = c * 256 + tid;
    int f = (mask[tok] >> e) & 1;
    sd[tid] = f;
    __syncthreads();
    for (int s = 1; s < 256; s <<= 1) {
      int v = (tid >= s) ? sd[tid - s] : 0;
      __syncthreads();
      sd[tid] += v;
      __syncthreads();
    }
    if (f) perm[e * NTOK + base + sd[tid] - 1] = tok;
    int tot = sd[255];
    __syncthreads();
    if (tid == 0) base += tot;
    __syncthreads();
  }
  if (tid == 0) cnt[e] = base;
}

__global__ void cbase_k(const int* __restrict__ cnt, int* __restrict__ cbase) {
  if (threadIdx.x == 0) {
    int b = 0;
    for (int e = 0; e < NEXP; ++e) { cbase[e] = b; b += cnt[e]; }
  }
}

__global__ void f2b_k(const float* __restrict__ src, u16* __restrict__ dst, long n) {
  long i = (long)blockIdx.x * 256 + threadIdx.x;
  if (i < n) dst[i] = f2bf(src[i]);
}

__global__ void f2bsplit_k(const float* __restrict__ src, u16* __restrict__ dh,
                           u16* __restrict__ dl, long n) {
  long i = (long)blockIdx.x * 256 + threadIdx.x;
  if (i < n) { u16 h, l; split2(src[i], h, l); dh[i] = h; dl[i] = l; }
}

extern "C" void kernel_launch(void* const* d_in, const int* in_sizes, int n_in,
                              void* d_out, int out_size, void* d_ws, size_t ws_size,
                              hipStream_t stream) {
  (void)in_sizes; (void)n_in; (void)out_size; (void)ws_size;
  const float* x_in  = (const float*)d_in[0];
  const float* ln1_g = (const float*)d_in[4];
  const float* ln1_b = (const float*)d_in[5];
  const float* w_qkv = (const float*)d_in[6];
  const float* w_out = (const float*)d_in[7];
  const float* gatew = (const float*)d_in[8];
  const float* eg    = (const float*)d_in[9];
  const float* eu    = (const float*)d_in[10];
  const float* ed    = (const float*)d_in[11];
  const float* sg    = (const float*)d_in[12];
  const float* su    = (const float*)d_in[13];
  const float* sd    = (const float*)d_in[14];
  const float* ln2_g = (const float*)d_in[15];
  const float* ln2_b = (const float*)d_in[16];

  float* xc = (float*)d_out;
  char* W = (char*)d_ws;
  size_t off = 0;
  auto alloc = [&](size_t bytes) {
    size_t o = off; off = (off + bytes + 255) & ~(size_t)255; return o;
  };
  // ---- persistent region (~14.3 MB) ----
  size_t o_cos  = alloc((size_t)S_LEN * HDIM * 4);
  size_t o_sin  = alloc((size_t)S_LEN * HDIM * 4);
  size_t o_xnh  = alloc((size_t)NTOK * DM * 2);
  size_t o_xnl  = alloc((size_t)NTOK * DM * 2);
  size_t o_comb = alloc((size_t)NTOK * 4 * 4);
  size_t o_mask = alloc((size_t)NTOK * 4);
  size_t o_perm = alloc((size_t)NEXP * NTOK * 4);
  size_t o_cnt  = alloc(256);
  size_t o_cb   = alloc(256);
  // ---- region A (union, 103.8 MB) ----
  const size_t EGU_B = (size_t)NEXP * FF2 * DM * 2;
  const size_t SGU_B = (size_t)FF2 * DM * 2;
  const size_t SD_B  = (size_t)DM * FF * 2;
  const size_t A_BYTES = 2 * EGU_B + 2 * SGU_B + 2 * SD_B;
  size_t oA = alloc(A_BYTES);
  // attention view of A
  size_t o_qkv = oA;
  size_t o_qph = oA + (size_t)NTOK * 3 * DM * 4;
  size_t o_qpl = o_qph + (size_t)NBH * S_LEN * HDP * 2;
  size_t o_kph = o_qpl + (size_t)NBH * S_LEN * HDP * 2;
  size_t o_kpl = o_kph + (size_t)NBH * S_LEN * HDP * 2;
  size_t o_vth = o_kpl + (size_t)NBH * S_LEN * HDP * 2;
  size_t o_vtl = o_vth + (size_t)NBH * HDP * S_LEN * 2;
  size_t o_omh = o_vtl + (size_t)NBH * HDP * S_LEN * 2;
  size_t o_oml = o_omh + (size_t)NTOK * DM * 2;
  // moe view of A
  size_t o_eguh = oA;
  size_t o_egul = oA + EGU_B;
  size_t o_sguh = oA + 2 * EGU_B;
  size_t o_sgul = o_sguh + SGU_B;
  size_t o_sdh  = o_sgul + SGU_B;
  size_t o_sdl  = o_sdh + SD_B;
  size_t o_edh  = oA;
  size_t o_edl  = oA + (size_t)NEXP * DM * FF * 2;
  // ---- region H (union, 100.7 MB) ----
  const size_t H_BYTES = (size_t)2 * HBROWS * FF * 2;
  size_t oH = alloc(H_BYTES);
  size_t o_wqh = oH;
  size_t o_wql = o_wqh + (size_t)3 * DM * DM * 2;
  size_t o_woh = o_wql + (size_t)3 * DM * DM * 2;
  size_t o_wol = o_woh + (size_t)DM * DM * 2;
  size_t o_hbh = oH;
  size_t o_hbl = oH + (size_t)HBROWS * FF * 2;

  float* cosT = (float*)(W + o_cos);
  float* sinT = (float*)(W + o_sin);
  u16*   xnh  = (u16*)(W + o_xnh);
  u16*   xnl  = (u16*)(W + o_xnl);
  float* comb = (float*)(W + o_comb);
  int* maskb  = (int*)(W + o_mask);
  int* permb  = (int*)(W + o_perm);
  int* cntb   = (int*)(W + o_cnt);
  int* cbaseb = (int*)(W + o_cb);
  float* qkv  = (float*)(W + o_qkv);
  u16 *qph = (u16*)(W + o_qph), *qpl = (u16*)(W + o_qpl);
  u16 *kph = (u16*)(W + o_kph), *kpl = (u16*)(W + o_kpl);
  u16 *vth = (u16*)(W + o_vth), *vtl = (u16*)(W + o_vtl);
  u16 *omh = (u16*)(W + o_omh), *oml = (u16*)(W + o_oml);
  u16 *eguh = (u16*)(W + o_eguh), *egul = (u16*)(W + o_egul);
  u16 *sguh = (u16*)(W + o_sguh), *sgul = (u16*)(W + o_sgul);
  u16 *sdh = (u16*)(W + o_sdh), *sdl = (u16*)(W + o_sdl);
  u16 *edh = (u16*)(W + o_edh), *edl = (u16*)(W + o_edl);
  u16 *wqh = (u16*)(W + o_wqh), *wql = (u16*)(W + o_wql);
  u16 *woh = (u16*)(W + o_woh), *wol = (u16*)(W + o_wol);
  u16 *hbh = (u16*)(W + o_hbh), *hbl = (u16*)(W + o_hbl);

  const long ND = (long)NTOK * DM;
  const int gND = (int)((ND + 255) / 256);

  hipMemcpyAsync(xc, x_in, (size_t)ND * 4, hipMemcpyDeviceToDevice, stream);
  rope_tables_k<<<S_LEN, HDIM, 0, stream>>>(cosT, sinT);

  dim3 tb(32, 8, 1);
  for (int l = 0; l < 2; ++l) {
    const float* wqkv_l = w_qkv + (size_t)l * DM * 3 * DM;
    const float* wout_l = w_out + (size_t)l * DM * DM;
    const float* gw_l   = gatew + (size_t)l * DM * 4;
    const float* eg_l = eg + (size_t)l * NEXP * DM * FF;
    const float* eu_l = eu + (size_t)l * NEXP * DM * FF;
    const float* ed_l = ed + (size_t)l * NEXP * FF * DM;
    const float* sg_l = sg + (size_t)l * DM * FF;
    const float* su_l = su + (size_t)l * DM * FF;
    const float* sd_l = sd + (size_t)l * FF * DM;

    // attention weights into region H (hb is dead here)
    wconv_t<<<dim3(3 * DM / 32, DM / 32, 1), tb, 0, stream>>>(wqkv_l, wqh, wql, DM, 3 * DM, -1, 0, 0);
    wconv_t<<<dim3(DM / 32, DM / 32, 1), tb, 0, stream>>>(wout_l, woh, wol, DM, DM, -1, 0, 0);

    // --- attention (fp32-equivalent via bf16x3 + flash) ---
    ln_k<<<NTOK, 256, 0, stream>>>(xc, ln1_g + l * DM, ln1_b + l * DM, nullptr, xnh, xnl);
    gemm3_nt<0><<<dim3(3 * DM >> 7, NTOK >> 7, 1), 256, 0, stream>>>(
        xnh, xnl, wqh, wql, qkv, NTOK, 3 * DM, DM, DM, DM, 0, 0, 0, 1, nullptr, nullptr);
    rope_apply_k<<<NTOK, 256, 0, stream>>>(qkv, cosT, sinT, qph, qpl, kph, kpl);
    v_transpose_k<<<dim3(S_LEN / 32, HDP / 32, NBH), tb, 0, stream>>>(qkv, vth, vtl);
    fattn_k<<<dim3(NBH, S_LEN / 64), dim3(256), 0, stream>>>(
        qph, qpl, kph, kpl, vth, vtl, omh, oml, 0.10206207261596575f);
    gemm3_nt<3><<<dim3(DM >> 7, NTOK >> 7, 2), 256, 0, stream>>>(
        omh, oml, woh, wol, xc, NTOK, DM, DM, DM, DM, 0, 0, 0, 2, nullptr, nullptr);

    // --- router + deterministic expert compaction (CSR) ---
    router_k<<<NTOK / 4, 256, 0, stream>>>(xc, gw_l, comb, maskb);
    scan_k<<<NEXP, 256, 0, stream>>>(maskb, permb, cntb);
    cbase_k<<<1, 64, 0, stream>>>(cntb, cbaseb);

    if (l == 0) {
      wconv_t<<<dim3(FF / 32, DM / 32, 1), tb, 0, stream>>>(sg_l, sguh, sgul, DM, FF, 0, 0, 0);
      wconv_t<<<dim3(FF / 32, DM / 32, 1), tb, 0, stream>>>(su_l, sguh, sgul, DM, FF, 1, 0, 0);
      wconv_t<<<dim3(DM / 32, FF / 32, 1), tb, 0, stream>>>(sd_l, sdh, sdl, FF, DM, -1, 0, 0);
      wconv_t<<<dim3(FF / 32, DM / 32, NEXP), tb, 0, stream>>>(
          eg_l, eguh, egul, DM, FF, 0, (long)DM * FF, (long)FF2 * DM);
      wconv_t<<<dim3(FF / 32, DM / 32, NEXP), tb, 0, stream>>>(
          eu_l, eguh, egul, DM, FF, 1, (long)DM * FF, (long)FF2 * DM);

      f2bsplit_k<<<gND, 256, 0, stream>>>(xc, xnh, xnl, ND);
      // shared expert: fused gu+silu -> hb[0..NTOK), down atomic into xc
      gemm3_nt<5><<<dim3(FF2 >> 7, NTOK >> 7, 1), 256, 0, stream>>>(
          xnh, xnl, sguh, sgul, nullptr, NTOK, FF2, DM, DM, DM, 0, 0, 0, 1, hbh, hbl);
      gemm3_nt<3><<<dim3(DM >> 7, NTOK >> 7, 4), 256, 0, stream>>>(
          hbh, hbl, sdh, sdl, xc, NTOK, DM, FF, FF, FF, 0, 0, 0, 4, nullptr, nullptr);
      // all 4 routed experts batched (z = expert)
      gemm3i_nt<5><<<dim3(FF2 >> 7, NTOK >> 7, NEXP), 256, 0, stream>>>(
          xnh, xnl, eguh, egul, nullptr, FF2, DM, DM, DM, FF2,
          permb, cntb, cbaseb, 1, (long)FF2 * DM, hbh, hbl, comb);
      wconv_t<<<dim3(DM / 32, FF / 32, NEXP), tb, 0, stream>>>(
          ed_l, edh, edl, FF, DM, -1, (long)FF * DM, (long)DM * FF);
      gemm3i_nt<1><<<dim3(DM >> 7, NTOK >> 7, NEXP * 4), 256, 0, stream>>>(
          hbh, hbl, edh, edl, xc, DM, FF, FF, FF, DM,
          permb, cntb, cbaseb, 4, (long)DM * FF, nullptr, nullptr, nullptr);
    } else {
      // layer-1: plain bf16 path -> convert hi only (skip lo writes)
      wconv_t<<<dim3(FF / 32, DM / 32, 1), tb, 0, stream>>>(sg_l, sguh, nullptr, DM, FF, 0, 0, 0);
      wconv_t<<<dim3(FF / 32, DM / 32, 1), tb, 0, stream>>>(su_l, sguh, nullptr, DM, FF, 1, 0, 0);
      wconv_t<<<dim3(DM / 32, FF / 32, 1), tb, 0, stream>>>(sd_l, sdh, nullptr, FF, DM, -1, 0, 0);
      wconv_t<<<dim3(FF / 32, DM / 32, NEXP), tb, 0, stream>>>(
          eg_l, eguh, nullptr, DM, FF, 0, (long)DM * FF, (long)FF2 * DM);
      wconv_t<<<dim3(FF / 32, DM / 32, NEXP), tb, 0, stream>>>(
          eu_l, eguh, nullptr, DM, FF, 1, (long)DM * FF, (long)FF2 * DM);

      f2b_k<<<gND, 256, 0, stream>>>(xc, xnh, ND);
      gemm_nt<5><<<dim3(FF2 >> 7, NTOK >> 7, 1), 256, 0, stream>>>(
          xnh, sguh, nullptr, NTOK, FF2, DM, DM, DM, 0, 0, 0, 1, hbh);
      gemm_nt<3><<<dim3(DM >> 7, NTOK >> 7, 4), 256, 0, stream>>>(
          hbh, sdh, xc, NTOK, DM, FF, FF, FF, 0, 0, 0, 4, nullptr);
      gemmi_nt<5><<<dim3(FF2 >> 7, NTOK >> 7, NEXP), 256, 0, stream>>>(
          xnh, eguh, nullptr, FF2, DM, DM, DM, FF2,
          permb, cntb, cbaseb, 1, (long)FF2 * DM, hbh, comb);
      wconv_t<<<dim3(DM / 32, FF / 32, NEXP), tb, 0, stream>>>(
          ed_l, edh, nullptr, FF, DM, -1, (long)FF * DM, (long)DM * FF);
      gemmi_nt<3><<<dim3(DM >> 7, NTOK >> 7, NEXP * 4), 256, 0, stream>>>(
          hbh, edh, xc, DM, FF, FF, FF, DM,
          permb, cntb, cbaseb, 4, (long)DM * FF, nullptr, nullptr);
    }
    ln_k<<<NTOK, 256, 0, stream>>>(xc, ln2_g + l * DM, ln2_b + l * DM, xc, nullptr, nullptr);
  }
}

// Round 13
// 1839.084 us; speedup vs baseline: 1.2287x; 1.0273x over previous
//
#include <hip/hip_runtime.h>
#include <stdint.h>

#define S_LEN 2048
#define DM    768
#define NHEAD 8
#define HDIM  96
#define HDP   128
#define FF    3072
#define FF2   6144
#define NEXP  4
#define NTOK  4096
#define NBH   16
#define HBROWS (2 * NTOK)

typedef unsigned short u16;
typedef short bf16x8 __attribute__((ext_vector_type(8)));
typedef float f32x4 __attribute__((ext_vector_type(4)));
typedef __attribute__((address_space(1))) void* gptr_t;
typedef __attribute__((address_space(3))) void* lptr_t;

__device__ __forceinline__ u16 f2bf(float f) {
  union { float f; uint32_t u; } v; v.f = f;
  uint32_t r = v.u + 0x7FFFu + ((v.u >> 16) & 1u);
  return (u16)(r >> 16);
}
__device__ __forceinline__ float bf2f(u16 h) {
  union { uint32_t u; float f; } v; v.u = ((uint32_t)h) << 16;
  return v.f;
}
__device__ __forceinline__ void split2(float f, u16& hi, u16& lo) {
  u16 h = f2bf(f);
  lo = f2bf(f - bf2f(h));
  hi = h;
}
__device__ __forceinline__ float siluf(float g) {
  return g / (1.0f + expf(-g));
}
__device__ __forceinline__ void gload16(const void* g, void* l) {
  __builtin_amdgcn_global_load_lds((gptr_t)(void*)g, (lptr_t)l, 16, 0, 0);
}
// GEMM-tile LDS swizzle (64B rows): chunk bits 4-5 XOR row bits 1-2 (byte 7-8).
__device__ __forceinline__ int swz(int byte) {
  return byte ^ (((byte >> 7) & 3) << 4);
}

// ---------------------------------------------------------------------------
// Plain NT GEMM, 2-phase double-buffered. C[M,N] = A[M,K] @ B[N,K]^T.
// Grid: (N/128, M/128, batch*kspl).
// MODE: 0 f32, 2 bf16, 3 atomic f32, 5 fused gate/up silu -> hb bf16.
// ---------------------------------------------------------------------------
template<int MODE>
__global__ __launch_bounds__(256) void gemm_nt(
    const u16* __restrict__ A, const u16* __restrict__ B, void* __restrict__ Cv,
    int M, int N, int K, int lda, int ldb, long sA, long sB, long sC, int kspl,
    u16* __restrict__ hb)
{
  __shared__ u16 As[2][128 * 32];
  __shared__ u16 Bs[2][128 * 32];
  const int z = blockIdx.z;
  const int bh = z / kspl;
  const int kc = z - bh * kspl;
  const u16* Az = A + (long)bh * sA;
  const u16* Bz = B + (long)bh * sB;
  const int brow = blockIdx.y << 7;
  const int bcol = blockIdx.x << 7;
  const int tid = threadIdx.x;
  const int wid = tid >> 6;
  const int lane = tid & 63;
  const int wr = (wid >> 1) << 6;
  const int wc = (wid & 1) << 6;

  f32x4 acc[4][4] = {};
  const int a0 = (wid << 11) + (lane << 4);

  auto stage = [&](int buf, int k0) {
#pragma unroll
    for (int c = 0; c < 2; ++c) {
      int ab = a0 + (c << 10);
      int lb = swz(ab);
      int row = ab >> 6;
      int kcol = (lb & 63) >> 1;
      int ld = (wid << 11) + (c << 10);
      gload16(Az + (long)(brow + row) * lda + (k0 + kcol), (char*)As[buf] + ld);
      gload16(Bz + (long)(bcol + row) * ldb + (k0 + kcol), (char*)Bs[buf] + ld);
    }
  };

  const int kt = K / kspl;
  const int kbeg = kc * kt;
  const int nt = kt >> 5;
  stage(0, kbeg);
  __syncthreads();
  for (int t = 0; t < nt; ++t) {
    const int cur = t & 1;
    if (t + 1 < nt) stage(cur ^ 1, kbeg + ((t + 1) << 5));
    bf16x8 af[4], bfr[4];
    const int lr = lane & 15;
    const int lk = (lane >> 4) << 4;
#pragma unroll
    for (int m = 0; m < 4; ++m)
      af[m] = *(const bf16x8*)((const char*)As[cur] + swz((((wr + m * 16 + lr) << 6) + lk)));
#pragma unroll
    for (int n = 0; n < 4; ++n)
      bfr[n] = *(const bf16x8*)((const char*)Bs[cur] + swz((((wc + n * 16 + lr) << 6) + lk)));
#pragma unroll
    for (int m = 0; m < 4; ++m)
#pragma unroll
      for (int n = 0; n < 4; ++n)
        acc[m][n] = __builtin_amdgcn_mfma_f32_16x16x32_bf16(af[m], bfr[n], acc[m][n], 0, 0, 0);
    if (t + 1 < nt) __syncthreads();
  }

  const int crow0 = brow + wr + ((lane >> 4) << 2);
  const int ccol0 = bcol + wc + (lane & 15);
  const long cbase = (long)bh * sC;
  if constexpr (MODE == 5) {
    const int pbase = (bcol + wc) >> 5;
#pragma unroll
    for (int m = 0; m < 4; ++m)
#pragma unroll
      for (int np = 0; np < 2; ++np)
#pragma unroll
        for (int j = 0; j < 4; ++j) {
          int r = crow0 + m * 16 + j;
          float g = acc[m][2 * np][j], u = acc[m][2 * np + 1][j];
          int hcol = ((pbase + np) << 4) + (lane & 15);
          hb[(long)r * FF + hcol] = f2bf(siluf(g) * u);
        }
  } else {
#pragma unroll
    for (int m = 0; m < 4; ++m)
#pragma unroll
      for (int n = 0; n < 4; ++n)
#pragma unroll
        for (int j = 0; j < 4; ++j) {
          long idx = cbase + (long)(crow0 + m * 16 + j) * N + (ccol0 + n * 16);
          float v = acc[m][n][j];
          if constexpr (MODE == 2) ((u16*)Cv)[idx] = f2bf(v);
          else if constexpr (MODE == 3) unsafeAtomicAdd((float*)Cv + idx, v);
          else ((float*)Cv)[idx] = v;
        }
  }
}

// ---------------------------------------------------------------------------
// Split (bf16x3) NT GEMM, dense. MODE: 0 f32, 3 atomic f32, 5 fused gu silu.
// ---------------------------------------------------------------------------
template<int MODE>
__global__ __launch_bounds__(256) void gemm3_nt(
    const u16* __restrict__ Ah, const u16* __restrict__ Al,
    const u16* __restrict__ Bh, const u16* __restrict__ Bl,
    float* __restrict__ C,
    int M, int N, int K, int lda, int ldb, long sA, long sB, long sC, int kspl,
    u16* __restrict__ hbh, u16* __restrict__ hbl)
{
  __shared__ u16 Ash[2][128 * 32], Asl[2][128 * 32];
  __shared__ u16 Bsh[2][128 * 32], Bsl[2][128 * 32];
  const int z = blockIdx.z;
  const int bh = z / kspl;
  const int kc = z - bh * kspl;
  const u16* Azh = Ah + (long)bh * sA;
  const u16* Azl = Al + (long)bh * sA;
  const u16* Bzh = Bh + (long)bh * sB;
  const u16* Bzl = Bl + (long)bh * sB;
  const int brow = blockIdx.y << 7;
  const int bcol = blockIdx.x << 7;
  const int tid = threadIdx.x;
  const int wid = tid >> 6;
  const int lane = tid & 63;
  const int wr = (wid >> 1) << 6;
  const int wc = (wid & 1) << 6;

  f32x4 acc[4][4] = {};
  const int a0 = (wid << 11) + (lane << 4);

  auto stage = [&](int buf, int k0) {
#pragma unroll
    for (int c = 0; c < 2; ++c) {
      int ab = a0 + (c << 10);
      int lb = swz(ab);
      int row = ab >> 6;
      int kcol = (lb & 63) >> 1;
      long ao = (long)(brow + row) * lda + (k0 + kcol);
      long bo = (long)(bcol + row) * ldb + (k0 + kcol);
      int ld = (wid << 11) + (c << 10);
      gload16(Azh + ao, (char*)Ash[buf] + ld);
      gload16(Azl + ao, (char*)Asl[buf] + ld);
      gload16(Bzh + bo, (char*)Bsh[buf] + ld);
      gload16(Bzl + bo, (char*)Bsl[buf] + ld);
    }
  };

  const int kt = K / kspl;
  const int kbeg = kc * kt;
  const int nt = kt >> 5;
  stage(0, kbeg);
  __syncthreads();
  for (int t = 0; t < nt; ++t) {
    const int cur = t & 1;
    if (t + 1 < nt) stage(cur ^ 1, kbeg + ((t + 1) << 5));
    const int lr = lane & 15;
    const int lk = (lane >> 4) << 4;
    bf16x8 ah[4], al[4], bh_[4], bl[4];
#pragma unroll
    for (int m = 0; m < 4; ++m) {
      int off = swz(((wr + m * 16 + lr) << 6) + lk);
      ah[m] = *(const bf16x8*)((const char*)Ash[cur] + off);
      al[m] = *(const bf16x8*)((const char*)Asl[cur] + off);
    }
#pragma unroll
    for (int n = 0; n < 4; ++n) {
      int off = swz(((wc + n * 16 + lr) << 6) + lk);
      bh_[n] = *(const bf16x8*)((const char*)Bsh[cur] + off);
      bl[n] = *(const bf16x8*)((const char*)Bsl[cur] + off);
    }
#pragma unroll
    for (int m = 0; m < 4; ++m)
#pragma unroll
      for (int n = 0; n < 4; ++n) {
        acc[m][n] = __builtin_amdgcn_mfma_f32_16x16x32_bf16(al[m], bh_[n], acc[m][n], 0, 0, 0);
        acc[m][n] = __builtin_amdgcn_mfma_f32_16x16x32_bf16(ah[m], bl[n], acc[m][n], 0, 0, 0);
        acc[m][n] = __builtin_amdgcn_mfma_f32_16x16x32_bf16(ah[m], bh_[n], acc[m][n], 0, 0, 0);
      }
    if (t + 1 < nt) __syncthreads();
  }

  const int crow0 = brow + wr + ((lane >> 4) << 2);
  const int ccol0 = bcol + wc + (lane & 15);
  const long cbase = (long)bh * sC;
  if constexpr (MODE == 5) {
    const int pbase = (bcol + wc) >> 5;
#pragma unroll
    for (int m = 0; m < 4; ++m)
#pragma unroll
      for (int np = 0; np < 2; ++np)
#pragma unroll
        for (int j = 0; j < 4; ++j) {
          int r = crow0 + m * 16 + j;
          float g = acc[m][2 * np][j], u = acc[m][2 * np + 1][j];
          float h = siluf(g) * u;
          int hcol = ((pbase + np) << 4) + (lane & 15);
          u16 hh, ll; split2(h, hh, ll);
          hbh[(long)r * FF + hcol] = hh;
          hbl[(long)r * FF + hcol] = ll;
        }
  } else {
#pragma unroll
    for (int m = 0; m < 4; ++m)
#pragma unroll
      for (int n = 0; n < 4; ++n)
#pragma unroll
        for (int j = 0; j < 4; ++j) {
          long idx = cbase + (long)(crow0 + m * 16 + j) * N + (ccol0 + n * 16);
          if constexpr (MODE == 3) unsafeAtomicAdd(&C[idx], acc[m][n][j]);
          else C[idx] = acc[m][n][j];
        }
  }
}

// ---------------------------------------------------------------------------
// Batched indirect split GEMM over experts (blockIdx.z = e*kspl+kc).
// MODE 5: gather-A via perm[e], fused gu silu * comb -> hb rows cbase[e]+r.
// MODE 1: compact-A rows cbase[e]+r (clamped), scatter-atomic f32.
// ---------------------------------------------------------------------------
template<int MODE>
__global__ __launch_bounds__(256) void gemm3i_nt(
    const u16* __restrict__ Ah, const u16* __restrict__ Al,
    const u16* __restrict__ Bh, const u16* __restrict__ Bl,
    float* __restrict__ C, int N, int K, int lda, int ldb, int ldc,
    const int* __restrict__ perm, const int* __restrict__ cnt,
    const int* __restrict__ cbase, int kspl, long wstride,
    u16* __restrict__ hbh, u16* __restrict__ hbl, const float* __restrict__ comb)
{
  const int z = blockIdx.z;
  const int e = z / kspl;
  const int kc = z - e * kspl;
  const int cn = cnt[e];
  const int brow = blockIdx.y << 7;
  if (brow >= cn) return;
  const int cb = cbase[e];
  const int* pe = perm + e * NTOK;
  const u16* Bhe = Bh + (long)e * wstride;
  const u16* Ble = Bl + (long)e * wstride;
  __shared__ u16 Ash[2][128 * 32], Asl[2][128 * 32];
  __shared__ u16 Bsh[2][128 * 32], Bsl[2][128 * 32];
  const int bcol = blockIdx.x << 7;
  const int tid = threadIdx.x;
  const int wid = tid >> 6;
  const int lane = tid & 63;
  const int wr = (wid >> 1) << 6;
  const int wc = (wid & 1) << 6;

  f32x4 acc[4][4] = {};
  const int a0 = (wid << 11) + (lane << 4);

  int arow[2];
#pragma unroll
  for (int c = 0; c < 2; ++c) {
    int ab = a0 + (c << 10);
    int row = ab >> 6;
    int g = brow + row;
    if constexpr (MODE == 5) {
      arow[c] = (g < cn) ? pe[g] : pe[brow];
    } else {
      arow[c] = cb + ((g < cn) ? g : (cn - 1));
    }
  }

  auto stage = [&](int buf, int k0) {
#pragma unroll
    for (int c = 0; c < 2; ++c) {
      int ab = a0 + (c << 10);
      int lb = swz(ab);
      int row = ab >> 6;
      int kcol = (lb & 63) >> 1;
      int ld = (wid << 11) + (c << 10);
      gload16(Ah + (long)arow[c] * lda + (k0 + kcol), (char*)Ash[buf] + ld);
      gload16(Al + (long)arow[c] * lda + (k0 + kcol), (char*)Asl[buf] + ld);
      long bo = (long)(bcol + row) * ldb + (k0 + kcol);
      gload16(Bhe + bo, (char*)Bsh[buf] + ld);
      gload16(Ble + bo, (char*)Bsl[buf] + ld);
    }
  };

  const int kt = K / kspl;
  const int kbeg = kc * kt;
  const int nt = kt >> 5;
  stage(0, kbeg);
  __syncthreads();
  for (int t = 0; t < nt; ++t) {
    const int cur = t & 1;
    if (t + 1 < nt) stage(cur ^ 1, kbeg + ((t + 1) << 5));
    const int lr = lane & 15;
    const int lk = (lane >> 4) << 4;
    bf16x8 ah[4], al[4], bh_[4], bl[4];
#pragma unroll
    for (int m = 0; m < 4; ++m) {
      int off = swz(((wr + m * 16 + lr) << 6) + lk);
      ah[m] = *(const bf16x8*)((const char*)Ash[cur] + off);
      al[m] = *(const bf16x8*)((const char*)Asl[cur] + off);
    }
#pragma unroll
    for (int n = 0; n < 4; ++n) {
      int off = swz(((wc + n * 16 + lr) << 6) + lk);
      bh_[n] = *(const bf16x8*)((const char*)Bsh[cur] + off);
      bl[n] = *(const bf16x8*)((const char*)Bsl[cur] + off);
    }
#pragma unroll
    for (int m = 0; m < 4; ++m)
#pragma unroll
      for (int n = 0; n < 4; ++n) {
        acc[m][n] = __builtin_amdgcn_mfma_f32_16x16x32_bf16(al[m], bh_[n], acc[m][n], 0, 0, 0);
        acc[m][n] = __builtin_amdgcn_mfma_f32_16x16x32_bf16(ah[m], bl[n], acc[m][n], 0, 0, 0);
        acc[m][n] = __builtin_amdgcn_mfma_f32_16x16x32_bf16(ah[m], bh_[n], acc[m][n], 0, 0, 0);
      }
    if (t + 1 < nt) __syncthreads();
  }

  const int crow0 = brow + wr + ((lane >> 4) << 2);
  const int ccol0 = bcol + wc + (lane & 15);
  if constexpr (MODE == 5) {
    const int pbase = (bcol + wc) >> 5;
#pragma unroll
    for (int m = 0; m < 4; ++m)
#pragma unroll
      for (int j = 0; j < 4; ++j) {
        int r = crow0 + m * 16 + j;
        if (r < cn) {
          float w = comb[pe[r] * 4 + e];
#pragma unroll
          for (int np = 0; np < 2; ++np) {
            float g = acc[m][2 * np][j], u = acc[m][2 * np + 1][j];
            float h = siluf(g) * u * w;
            int hcol = ((pbase + np) << 4) + (lane & 15);
            u16 hh, ll; split2(h, hh, ll);
            hbh[(long)(cb + r) * FF + hcol] = hh;
            hbl[(long)(cb + r) * FF + hcol] = ll;
          }
        }
      }
  } else {
#pragma unroll
    for (int m = 0; m < 4; ++m)
#pragma unroll
      for (int n = 0; n < 4; ++n)
#pragma unroll
        for (int j = 0; j < 4; ++j) {
          int r = crow0 + m * 16 + j;
          if (r < cn) {
            int col = ccol0 + n * 16;
            unsafeAtomicAdd(&C[(long)pe[r] * ldc + col], acc[m][n][j]);
          }
        }
  }
}

// ---------------------------------------------------------------------------
// Batched indirect plain bf16 GEMM over experts (layer-1).
// MODE 5: gather-A, fused gu -> hb rows cbase[e]+r. MODE 3: compact-A, scatter.
// ---------------------------------------------------------------------------
template<int MODE>
__global__ __launch_bounds__(256) void gemmi_nt(
    const u16* __restrict__ A, const u16* __restrict__ B, void* __restrict__ Cv,
    int N, int K, int lda, int ldb, int ldc,
    const int* __restrict__ perm, const int* __restrict__ cnt,
    const int* __restrict__ cbase, int kspl, long wstride,
    u16* __restrict__ hb, const float* __restrict__ comb)
{
  const int z = blockIdx.z;
  const int e = z / kspl;
  const int kc = z - e * kspl;
  const int cn = cnt[e];
  const int brow = blockIdx.y << 7;
  if (brow >= cn) return;
  const int cb = cbase[e];
  const int* pe = perm + e * NTOK;
  const u16* Be = B + (long)e * wstride;
  __shared__ u16 As[2][128 * 32];
  __shared__ u16 Bs[2][128 * 32];
  const int bcol = blockIdx.x << 7;
  const int tid = threadIdx.x;
  const int wid = tid >> 6;
  const int lane = tid & 63;
  const int wr = (wid >> 1) << 6;
  const int wc = (wid & 1) << 6;

  f32x4 acc[4][4] = {};
  const int a0 = (wid << 11) + (lane << 4);

  int arow[2];
#pragma unroll
  for (int c = 0; c < 2; ++c) {
    int ab = a0 + (c << 10);
    int row = ab >> 6;
    int g = brow + row;
    if constexpr (MODE == 5) {
      arow[c] = (g < cn) ? pe[g] : pe[brow];
    } else {
      arow[c] = cb + ((g < cn) ? g : (cn - 1));
    }
  }

  auto stage = [&](int buf, int k0) {
#pragma unroll
    for (int c = 0; c < 2; ++c) {
      int ab = a0 + (c << 10);
      int lb = swz(ab);
      int row = ab >> 6;
      int kcol = (lb & 63) >> 1;
      int ld = (wid << 11) + (c << 10);
      gload16(A + (long)arow[c] * lda + (k0 + kcol), (char*)As[buf] + ld);
      gload16(Be + (long)(bcol + row) * ldb + (k0 + kcol), (char*)Bs[buf] + ld);
    }
  };

  const int kt = K / kspl;
  const int kbeg = kc * kt;
  const int nt = kt >> 5;
  stage(0, kbeg);
  __syncthreads();
  for (int t = 0; t < nt; ++t) {
    const int cur = t & 1;
    if (t + 1 < nt) stage(cur ^ 1, kbeg + ((t + 1) << 5));
    bf16x8 af[4], bfr[4];
    const int lr = lane & 15;
    const int lk = (lane >> 4) << 4;
#pragma unroll
    for (int m = 0; m < 4; ++m)
      af[m] = *(const bf16x8*)((const char*)As[cur] + swz((((wr + m * 16 + lr) << 6) + lk)));
#pragma unroll
    for (int n = 0; n < 4; ++n)
      bfr[n] = *(const bf16x8*)((const char*)Bs[cur] + swz((((wc + n * 16 + lr) << 6) + lk)));
#pragma unroll
    for (int m = 0; m < 4; ++m)
#pragma unroll
      for (int n = 0; n < 4; ++n)
        acc[m][n] = __builtin_amdgcn_mfma_f32_16x16x32_bf16(af[m], bfr[n], acc[m][n], 0, 0, 0);
    if (t + 1 < nt) __syncthreads();
  }

  const int crow0 = brow + wr + ((lane >> 4) << 2);
  const int ccol0 = bcol + wc + (lane & 15);
  if constexpr (MODE == 5) {
    const int pbase = (bcol + wc) >> 5;
#pragma unroll
    for (int m = 0; m < 4; ++m)
#pragma unroll
      for (int j = 0; j < 4; ++j) {
        int r = crow0 + m * 16 + j;
        if (r < cn) {
          float w = comb[pe[r] * 4 + e];
#pragma unroll
          for (int np = 0; np < 2; ++np) {
            float g = acc[m][2 * np][j], u = acc[m][2 * np + 1][j];
            int hcol = ((pbase + np) << 4) + (lane & 15);
            hb[(long)(cb + r) * FF + hcol] = f2bf(siluf(g) * u * w);
          }
        }
      }
  } else {
#pragma unroll
    for (int m = 0; m < 4; ++m)
#pragma unroll
      for (int n = 0; n < 4; ++n)
#pragma unroll
        for (int j = 0; j < 4; ++j) {
          int r = crow0 + m * 16 + j;
          if (r < cn) {
            int col = ccol0 + n * 16;
            unsafeAtomicAdd((float*)Cv + (long)pe[r] * ldc + col, acc[m][n][j]);
          }
        }
  }
}

// ---------------------------------------------------------------------------
// Fused flash attention. QK computed over exact K=96 (pad cols are zero).
// ---------------------------------------------------------------------------
__global__ __launch_bounds__(256, 2) void fattn_k(
    const u16* __restrict__ qh, const u16* __restrict__ ql,
    const u16* __restrict__ kh, const u16* __restrict__ kl,
    const u16* __restrict__ vth, const u16* __restrict__ vtl,
    u16* __restrict__ omh, u16* __restrict__ oml, float scale)
{
  __shared__ u16 Ksh[64 * 128], Ksl[64 * 128];
  __shared__ u16 Vsh[128 * 64], Vsl[128 * 64];
  const int bh = blockIdx.x;
  const int qt = blockIdx.y;
  const int tid = threadIdx.x, wid = tid >> 6, lane = tid & 63;
  const int lr = lane & 15, lg = lane >> 4;
  const int q0 = qt * 64 + wid * 16;
  const long bhoff = (long)bh * S_LEN * HDP;
  const u16* Qh = qh + bhoff;  const u16* Ql = ql + bhoff;
  const u16* Kgh = kh + bhoff; const u16* Kgl = kl + bhoff;
  const u16* Vgh = vth + bhoff; const u16* Vgl = vtl + bhoff;

  bf16x8 qfh[3], qfl[3];
#pragma unroll
  for (int kk = 0; kk < 3; ++kk) {
    long o = (long)(q0 + lr) * HDP + kk * 32 + lg * 8;
    qfh[kk] = *(const bf16x8*)(Qh + o);
    qfl[kk] = *(const bf16x8*)(Ql + o);
  }

  f32x4 oacc[6] = {};
  float rm[4], rls[4];
#pragma unroll
  for (int j = 0; j < 4; ++j) { rm[j] = -1e30f; rls[j] = 0.f; }

  for (int t = 0; t < S_LEN / 64; ++t) {
    __syncthreads();
#pragma unroll
    for (int c = 0; c < 4; ++c) {
      int off = (tid + (c << 8)) << 4;
      {
        int lb = off ^ ((((off >> 8) & 7)) << 4);
        int row = lb >> 8, colh = (lb & 255) >> 1;
        long src = (long)(t * 64 + row) * HDP + colh;
        gload16(Kgh + src, (char*)Ksh + off);
        gload16(Kgl + src, (char*)Ksl + off);
      }
      {
        int lb = off ^ ((((off >> 7) & 7)) << 4);
        int row = lb >> 7, colh = (lb & 127) >> 1;
        long src = (long)row * S_LEN + t * 64 + colh;
        gload16(Vgh + src, (char*)Vsh + off);
        gload16(Vgl + src, (char*)Vsl + off);
      }
    }
    __syncthreads();

    f32x4 sacc[4] = {};
#pragma unroll
    for (int kk = 0; kk < 3; ++kk) {
      bf16x8 kbh[4], kbl[4];
#pragma unroll
      for (int n = 0; n < 4; ++n) {
        int byte = ((n * 16 + lr) << 8) + (kk << 6) + (lg << 4);
        byte ^= ((byte >> 8) & 7) << 4;
        kbh[n] = *(const bf16x8*)((const char*)Ksh + byte);
        kbl[n] = *(const bf16x8*)((const char*)Ksl + byte);
      }
      __builtin_amdgcn_s_setprio(1);
#pragma unroll
      for (int n = 0; n < 4; ++n) {
        sacc[n] = __builtin_amdgcn_mfma_f32_16x16x32_bf16(qfl[kk], kbh[n], sacc[n], 0, 0, 0);
        sacc[n] = __builtin_amdgcn_mfma_f32_16x16x32_bf16(qfh[kk], kbl[n], sacc[n], 0, 0, 0);
        sacc[n] = __builtin_amdgcn_mfma_f32_16x16x32_bf16(qfh[kk], kbh[n], sacc[n], 0, 0, 0);
      }
      __builtin_amdgcn_s_setprio(0);
    }
    __syncthreads();

#pragma unroll
    for (int j = 0; j < 4; ++j) {
      float mx = fmaxf(fmaxf(sacc[0][j], sacc[1][j]),
                       fmaxf(sacc[2][j], sacc[3][j])) * scale;
      mx = fmaxf(mx, __shfl_xor(mx, 1));
      mx = fmaxf(mx, __shfl_xor(mx, 2));
      mx = fmaxf(mx, __shfl_xor(mx, 4));
      mx = fmaxf(mx, __shfl_xor(mx, 8));
      float mnew = fmaxf(rm[j], mx);
      float corr = __expf(rm[j] - mnew);
      rm[j] = mnew;
      float ps = 0.f;
#pragma unroll
      for (int n = 0; n < 4; ++n) {
        float p = __expf(sacc[n][j] * scale - mnew);
        sacc[n][j] = p; ps += p;
      }
      ps += __shfl_xor(ps, 1); ps += __shfl_xor(ps, 2);
      ps += __shfl_xor(ps, 4); ps += __shfl_xor(ps, 8);
      rls[j] = rls[j] * corr + ps;
#pragma unroll
      for (int n2 = 0; n2 < 6; ++n2) oacc[n2][j] *= corr;
    }

    char* Pwh = (char*)Ksh + (wid << 11);
    char* Pwl = (char*)Ksl + (wid << 11);
#pragma unroll
    for (int n = 0; n < 4; ++n)
#pragma unroll
      for (int j = 0; j < 4; ++j) {
        int row = lg * 4 + j;
        int byte = (row << 7) + ((n * 16 + lr) << 1);
        byte ^= ((byte >> 7) & 7) << 4;
        u16 h, l; split2(sacc[n][j], h, l);
        *(u16*)(Pwh + byte) = h;
        *(u16*)(Pwl + byte) = l;
      }
    bf16x8 pah[2], pal[2];
#pragma unroll
    for (int kk = 0; kk < 2; ++kk) {
      int byte = (lr << 7) + (kk << 6) + (lg << 4);
      byte ^= ((byte >> 7) & 7) << 4;
      pah[kk] = *(const bf16x8*)(Pwh + byte);
      pal[kk] = *(const bf16x8*)(Pwl + byte);
    }

#pragma unroll
    for (int kk = 0; kk < 2; ++kk) {
      bf16x8 vbh[6], vbl[6];
#pragma unroll
      for (int n2 = 0; n2 < 6; ++n2) {
        int byte = ((n2 * 16 + lr) << 7) + (kk << 6) + (lg << 4);
        byte ^= ((byte >> 7) & 7) << 4;
        vbh[n2] = *(const bf16x8*)((const char*)Vsh + byte);
        vbl[n2] = *(const bf16x8*)((const char*)Vsl + byte);
      }
      __builtin_amdgcn_s_setprio(1);
#pragma unroll
      for (int n2 = 0; n2 < 6; ++n2) {
        oacc[n2] = __builtin_amdgcn_mfma_f32_16x16x32_bf16(pal[kk], vbh[n2], oacc[n2], 0, 0, 0);
        oacc[n2] = __builtin_amdgcn_mfma_f32_16x16x32_bf16(pah[kk], vbl[n2], oacc[n2], 0, 0, 0);
        oacc[n2] = __builtin_amdgcn_mfma_f32_16x16x32_bf16(pah[kk], vbh[n2], oacc[n2], 0, 0, 0);
      }
      __builtin_amdgcn_s_setprio(0);
    }
  }

  const int b = bh >> 3, h = bh & 7;
#pragma unroll
  for (int j = 0; j < 4; ++j) {
    float inv = 1.0f / rls[j];
    int q = q0 + lg * 4 + j;
    long base = ((long)(b * S_LEN + q)) * DM + h * HDIM;
#pragma unroll
    for (int n2 = 0; n2 < 6; ++n2) {
      int d = n2 * 16 + lr;
      u16 hh, ll; split2(oacc[n2][j] * inv, hh, ll);
      omh[base + d] = hh; oml[base + d] = ll;
    }
  }
}

// ---------------------------------------------------------------------------
// fp32 [R][C] -> bf16 hi/lo [C][R] transpose+split, z-batched.
// ilv<0: linear rows; ilv in {0,1}: gate/up 16-row interleave. outl optional.
// ---------------------------------------------------------------------------
__global__ void wconv_t(const float* __restrict__ in, u16* __restrict__ outh,
                        u16* __restrict__ outl, int R, int C, int ilv,
                        long inStride, long outStride) {
  __shared__ float tile[32][33];
  long z = blockIdx.z;
  in += z * inStride; outh += z * outStride;
  if (outl) outl += z * outStride;
  int c0 = blockIdx.x << 5, r0 = blockIdx.y << 5;
  int tx = threadIdx.x;
  for (int rr = threadIdx.y; rr < 32; rr += 8)
    tile[rr][tx] = in[(long)(r0 + rr) * C + (c0 + tx)];
  __syncthreads();
  for (int rr = threadIdx.y; rr < 32; rr += 8) {
    u16 h, l; split2(tile[tx][rr], h, l);
    int f = c0 + rr;
    long orow = (ilv < 0) ? f : (((f >> 4) << 5) + (ilv << 4) + (f & 15));
    long o = orow * R + (r0 + tx);
    outh[o] = h;
    if (outl) outl[o] = l;
  }
}

__global__ __launch_bounds__(256) void ln_k(const float* __restrict__ in,
    const float* __restrict__ g, const float* __restrict__ b,
    float* __restrict__ outf, u16* __restrict__ outh, u16* __restrict__ outl) {
  int row = blockIdx.x;
  const float* x = in + (long)row * DM;
  int tid = threadIdx.x;
  float v[3], s = 0.f, ss = 0.f;
#pragma unroll
  for (int i = 0; i < 3; ++i) { v[i] = x[tid + (i << 8)]; s += v[i]; ss += v[i] * v[i]; }
  __shared__ float red[2][4];
  for (int o = 32; o; o >>= 1) { s += __shfl_down(s, o); ss += __shfl_down(ss, o); }
  int wid = tid >> 6, lane = tid & 63;
  if (!lane) { red[0][wid] = s; red[1][wid] = ss; }
  __syncthreads();
  s = red[0][0] + red[0][1] + red[0][2] + red[0][3];
  ss = red[1][0] + red[1][1] + red[1][2] + red[1][3];
  float mean = s * (1.f / DM);
  float var = ss * (1.f / DM) - mean * mean;
  float rs = rsqrtf(var + 1e-5f);
#pragma unroll
  for (int i = 0; i < 3; ++i) {
    int c = tid + (i << 8);
    float y = (v[i] - mean) * rs * g[c] + b[c];
    if (outf) outf[(long)row * DM + c] = y;
    if (outh) { u16 h, l; split2(y, h, l); outh[(long)row * DM + c] = h; outl[(long)row * DM + c] = l; }
  }
}

__global__ void rope_tables_k(float* __restrict__ cosT, float* __restrict__ sinT) {
  int s = blockIdx.x, d = threadIdx.x;
  int xc = s & 15, y = (s >> 4) & 15, t = s >> 8;
  int axis = d / 32, fi = d & 15;
  int coord = axis == 0 ? xc : (axis == 1 ? y : t);
  float inv = powf(10000.0f, -(float)fi / 16.0f);
  float ang = (float)coord * inv;
  cosT[s * HDIM + d] = cosf(ang);
  sinT[s * HDIM + d] = sinf(ang);
}

__global__ __launch_bounds__(256) void rope_apply_k(const float* __restrict__ qkv,
    const float* __restrict__ cosT, const float* __restrict__ sinT,
    u16* __restrict__ qh, u16* __restrict__ ql,
    u16* __restrict__ kh, u16* __restrict__ kl) {
  int bs = blockIdx.x;
  int b = bs >> 11, s = bs & 2047;
  const float* base = qkv + ((long)(b * S_LEN + s) * 3) * DM;
  for (int idx = threadIdx.x; idx < DM; idx += 256) {
    int h = idx / HDIM, d = idx - h * HDIM;
    float c = cosT[s * HDIM + d], sn = sinT[s * HDIM + d];
    int pair = (d < 48) ? idx + 48 : idx - 48;
    float qv = base[idx], kv = base[DM + idx];
    float qr = (d < 48) ? -base[pair] : base[pair];
    float kr = (d < 48) ? -base[DM + pair] : base[DM + pair];
    long o = ((long)(b * NHEAD + h) * S_LEN + s) * HDP + d;
    u16 hh, ll;
    split2(qv * c + qr * sn, hh, ll); qh[o] = hh; ql[o] = ll;
    split2(kv * c + kr * sn, hh, ll); kh[o] = hh; kl[o] = ll;
  }
  int t = threadIdx.x;
  int h = t >> 5, d = HDIM + (t & 31);
  long o = ((long)(b * NHEAD + h) * S_LEN + s) * HDP + d;
  qh[o] = 0; ql[o] = 0; kh[o] = 0; kl[o] = 0;
}

__global__ void v_transpose_k(const float* __restrict__ qkv,
                              u16* __restrict__ vh, u16* __restrict__ vl) {
  __shared__ float tile[32][33];
  int bh = blockIdx.z, b = bh >> 3, h = bh & 7;
  int s0 = blockIdx.x << 5, d0 = blockIdx.y << 5;
  int tx = threadIdx.x;
  for (int r = threadIdx.y; r < 32; r += 8) {
    int s = s0 + r, d = d0 + tx;
    float v = 0.f;
    if (d < HDIM) v = qkv[((long)(b * S_LEN + s) * 3 + 2) * DM + h * HDIM + d];
    tile[r][tx] = v;
  }
  __syncthreads();
  for (int r = threadIdx.y; r < 32; r += 8) {
    int d = d0 + r;
    u16 hh, ll; split2(tile[tx][r], hh, ll);
    long o = ((long)bh * HDP + d) * S_LEN + (s0 + tx);
    vh[o] = hh; vl[o] = ll;
  }
}

// Router: comb[tok][e] + top-2 bitmask per token.
__global__ __launch_bounds__(256) void router_k(const float* __restrict__ x,
    const float* __restrict__ gw, float* __restrict__ comb, int* __restrict__ mask) {
  int tok = blockIdx.x * 4 + (threadIdx.x >> 6);
  int lane = threadIdx.x & 63;
  const float* xr = x + (long)tok * DM;
  float a0 = 0, a1 = 0, a2 = 0, a3 = 0;
  for (int i = lane; i < DM; i += 64) {
    float xv = xr[i];
    const float* g = gw + i * 4;
    a0 += xv * g[0]; a1 += xv * g[1]; a2 += xv * g[2]; a3 += xv * g[3];
  }
  for (int o = 32; o; o >>= 1) {
    a0 += __shfl_down(a0, o); a1 += __shfl_down(a1, o);
    a2 += __shfl_down(a2, o); a3 += __shfl_down(a3, o);
  }
  if (lane == 0) {
    float p[4] = {a0, a1, a2, a3};
    float mx = fmaxf(fmaxf(p[0], p[1]), fmaxf(p[2], p[3]));
    float s = 0.f;
    for (int e = 0; e < 4; ++e) { p[e] = expf(p[e] - mx); s += p[e]; }
    for (int e = 0; e < 4; ++e) p[e] /= s;
    int i1 = 0;
    for (int e = 1; e < 4; ++e) if (p[e] > p[i1]) i1 = e;
    int i2 = -1;
    for (int e = 0; e < 4; ++e) if (e != i1 && (i2 < 0 || p[e] > p[i2])) i2 = e;
    float ssum = p[i1] + p[i2] + 1e-5f;
    float out[4] = {0, 0, 0, 0};
    out[i1] = p[i1] / ssum; out[i2] = p[i2] / ssum;
    for (int e = 0; e < 4; ++e) comb[tok * 4 + e] = out[e];
    mask[tok] = (1 << i1) | (1 << i2);
  }
}

// Deterministic per-expert compaction; one block per expert (grid = NEXP).
__global__ void scan_k(const int* __restrict__ mask, int* __restrict__ perm,
                       int* __restrict__ cnt) {
  __shared__ int sd[256];
  __shared__ int base;
  int tid = threadIdx.x;
  int e = blockIdx.x;
  if (tid == 0) base = 0;
  __syncthreads();
  for (int c = 0; c < NTOK / 256; ++c) {
    int tok = c * 256 + tid;
    int f = (mask[tok] >> e) & 1;
    sd[tid] = f;
    __syncthreads();
    for (int s = 1; s < 256; s <<= 1) {
      int v = (tid >= s) ? sd[tid - s] : 0;
      __syncthreads();
      sd[tid] += v;
      __syncthreads();
    }
    if (f) perm[e * NTOK + base + sd[tid] - 1] = tok;
    int tot = sd[255];
    __syncthreads();
    if (tid == 0) base += tot;
    __syncthreads();
  }
  if (tid == 0) cnt[e] = base;
}

__global__ void cbase_k(const int* __restrict__ cnt, int* __restrict__ cbase) {
  if (threadIdx.x == 0) {
    int b = 0;
    for (int e = 0; e < NEXP; ++e) { cbase[e] = b; b += cnt[e]; }
  }
}

__global__ void f2b_k(const float* __restrict__ src, u16* __restrict__ dst, long n) {
  long i = (long)blockIdx.x * 256 + threadIdx.x;
  if (i < n) dst[i] = f2bf(src[i]);
}

__global__ void f2bsplit_k(const float* __restrict__ src, u16* __restrict__ dh,
                           u16* __restrict__ dl, long n) {
  long i = (long)blockIdx.x * 256 + threadIdx.x;
  if (i < n) { u16 h, l; split2(src[i], h, l); dh[i] = h; dl[i] = l; }
}

extern "C" void kernel_launch(void* const* d_in, const int* in_sizes, int n_in,
                              void* d_out, int out_size, void* d_ws, size_t ws_size,
                              hipStream_t stream) {
  (void)in_sizes; (void)n_in; (void)out_size; (void)ws_size;
  const float* x_in  = (const float*)d_in[0];
  const float* ln1_g = (const float*)d_in[4];
  const float* ln1_b = (const float*)d_in[5];
  const float* w_qkv = (const float*)d_in[6];
  const float* w_out = (const float*)d_in[7];
  const float* gatew = (const float*)d_in[8];
  const float* eg    = (const float*)d_in[9];
  const float* eu    = (const float*)d_in[10];
  const float* ed    = (const float*)d_in[11];
  const float* sg    = (const float*)d_in[12];
  const float* su    = (const float*)d_in[13];
  const float* sd    = (const float*)d_in[14];
  const float* ln2_g = (const float*)d_in[15];
  const float* ln2_b = (const float*)d_in[16];

  float* xc = (float*)d_out;
  char* W = (char*)d_ws;
  size_t off = 0;
  auto alloc = [&](size_t bytes) {
    size_t o = off; off = (off + bytes + 255) & ~(size_t)255; return o;
  };
  // ---- persistent region (~14.3 MB) ----
  size_t o_cos  = alloc((size_t)S_LEN * HDIM * 4);
  size_t o_sin  = alloc((size_t)S_LEN * HDIM * 4);
  size_t o_xnh  = alloc((size_t)NTOK * DM * 2);
  size_t o_xnl  = alloc((size_t)NTOK * DM * 2);
  size_t o_comb = alloc((size_t)NTOK * 4 * 4);
  size_t o_mask = alloc((size_t)NTOK * 4);
  size_t o_perm = alloc((size_t)NEXP * NTOK * 4);
  size_t o_cnt  = alloc(256);
  size_t o_cb   = alloc(256);
  // ---- region A (union, 103.8 MB) ----
  const size_t EGU_B = (size_t)NEXP * FF2 * DM * 2;
  const size_t SGU_B = (size_t)FF2 * DM * 2;
  const size_t SD_B  = (size_t)DM * FF * 2;
  const size_t A_BYTES = 2 * EGU_B + 2 * SGU_B + 2 * SD_B;
  size_t oA = alloc(A_BYTES);
  // attention view of A
  size_t o_qkv = oA;
  size_t o_qph = oA + (size_t)NTOK * 3 * DM * 4;
  size_t o_qpl = o_qph + (size_t)NBH * S_LEN * HDP * 2;
  size_t o_kph = o_qpl + (size_t)NBH * S_LEN * HDP * 2;
  size_t o_kpl = o_kph + (size_t)NBH * S_LEN * HDP * 2;
  size_t o_vth = o_kpl + (size_t)NBH * S_LEN * HDP * 2;
  size_t o_vtl = o_vth + (size_t)NBH * HDP * S_LEN * 2;
  size_t o_omh = o_vtl + (size_t)NBH * HDP * S_LEN * 2;
  size_t o_oml = o_omh + (size_t)NTOK * DM * 2;
  // moe view of A
  size_t o_eguh = oA;
  size_t o_egul = oA + EGU_B;
  size_t o_sguh = oA + 2 * EGU_B;
  size_t o_sgul = o_sguh + SGU_B;
  size_t o_sdh  = o_sgul + SGU_B;
  size_t o_sdl  = o_sdh + SD_B;
  size_t o_edh  = oA;
  size_t o_edl  = oA + (size_t)NEXP * DM * FF * 2;
  // ---- region H (union, 100.7 MB) ----
  const size_t H_BYTES = (size_t)2 * HBROWS * FF * 2;
  size_t oH = alloc(H_BYTES);
  size_t o_wqh = oH;
  size_t o_wql = o_wqh + (size_t)3 * DM * DM * 2;
  size_t o_woh = o_wql + (size_t)3 * DM * DM * 2;
  size_t o_wol = o_woh + (size_t)DM * DM * 2;
  size_t o_hbh = oH;
  size_t o_hbl = oH + (size_t)HBROWS * FF * 2;

  float* cosT = (float*)(W + o_cos);
  float* sinT = (float*)(W + o_sin);
  u16*   xnh  = (u16*)(W + o_xnh);
  u16*   xnl  = (u16*)(W + o_xnl);
  float* comb = (float*)(W + o_comb);
  int* maskb  = (int*)(W + o_mask);
  int* permb  = (int*)(W + o_perm);
  int* cntb   = (int*)(W + o_cnt);
  int* cbaseb = (int*)(W + o_cb);
  float* qkv  = (float*)(W + o_qkv);
  u16 *qph = (u16*)(W + o_qph), *qpl = (u16*)(W + o_qpl);
  u16 *kph = (u16*)(W + o_kph), *kpl = (u16*)(W + o_kpl);
  u16 *vth = (u16*)(W + o_vth), *vtl = (u16*)(W + o_vtl);
  u16 *omh = (u16*)(W + o_omh), *oml = (u16*)(W + o_oml);
  u16 *eguh = (u16*)(W + o_eguh), *egul = (u16*)(W + o_egul);
  u16 *sguh = (u16*)(W + o_sguh), *sgul = (u16*)(W + o_sgul);
  u16 *sdh = (u16*)(W + o_sdh), *sdl = (u16*)(W + o_sdl);
  u16 *edh = (u16*)(W + o_edh), *edl = (u16*)(W + o_edl);
  u16 *wqh = (u16*)(W + o_wqh), *wql = (u16*)(W + o_wql);
  u16 *woh = (u16*)(W + o_woh), *wol = (u16*)(W + o_wol);
  u16 *hbh = (u16*)(W + o_hbh), *hbl = (u16*)(W + o_hbl);

  const long ND = (long)NTOK * DM;
  const int gND = (int)((ND + 255) / 256);

  hipMemcpyAsync(xc, x_in, (size_t)ND * 4, hipMemcpyDeviceToDevice, stream);
  rope_tables_k<<<S_LEN, HDIM, 0, stream>>>(cosT, sinT);

  dim3 tb(32, 8, 1);
  for (int l = 0; l < 2; ++l) {
    const float* wqkv_l = w_qkv + (size_t)l * DM * 3 * DM;
    const float* wout_l = w_out + (size_t)l * DM * DM;
    const float* gw_l   = gatew + (size_t)l * DM * 4;
    const float* eg_l = eg + (size_t)l * NEXP * DM * FF;
    const float* eu_l = eu + (size_t)l * NEXP * DM * FF;
    const float* ed_l = ed + (size_t)l * NEXP * FF * DM;
    const float* sg_l = sg + (size_t)l * DM * FF;
    const float* su_l = su + (size_t)l * DM * FF;
    const float* sd_l = sd + (size_t)l * FF * DM;

    // attention weights into region H (hb is dead here)
    wconv_t<<<dim3(3 * DM / 32, DM / 32, 1), tb, 0, stream>>>(wqkv_l, wqh, wql, DM, 3 * DM, -1, 0, 0);
    wconv_t<<<dim3(DM / 32, DM / 32, 1), tb, 0, stream>>>(wout_l, woh, wol, DM, DM, -1, 0, 0);

    // --- attention (fp32-equivalent via bf16x3 + flash) ---
    ln_k<<<NTOK, 256, 0, stream>>>(xc, ln1_g + l * DM, ln1_b + l * DM, nullptr, xnh, xnl);
    gemm3_nt<0><<<dim3(3 * DM >> 7, NTOK >> 7, 1), 256, 0, stream>>>(
        xnh, xnl, wqh, wql, qkv, NTOK, 3 * DM, DM, DM, DM, 0, 0, 0, 1, nullptr, nullptr);
    rope_apply_k<<<NTOK, 256, 0, stream>>>(qkv, cosT, sinT, qph, qpl, kph, kpl);
    v_transpose_k<<<dim3(S_LEN / 32, HDP / 32, NBH), tb, 0, stream>>>(qkv, vth, vtl);
    fattn_k<<<dim3(NBH, S_LEN / 64), dim3(256), 0, stream>>>(
        qph, qpl, kph, kpl, vth, vtl, omh, oml, 0.10206207261596575f);
    gemm3_nt<3><<<dim3(DM >> 7, NTOK >> 7, 2), 256, 0, stream>>>(
        omh, oml, woh, wol, xc, NTOK, DM, DM, DM, DM, 0, 0, 0, 2, nullptr, nullptr);

    // --- router + deterministic expert compaction (CSR) ---
    router_k<<<NTOK / 4, 256, 0, stream>>>(xc, gw_l, comb, maskb);
    scan_k<<<NEXP, 256, 0, stream>>>(maskb, permb, cntb);
    cbase_k<<<1, 64, 0, stream>>>(cntb, cbaseb);

    if (l == 0) {
      wconv_t<<<dim3(FF / 32, DM / 32, 1), tb, 0, stream>>>(sg_l, sguh, sgul, DM, FF, 0, 0, 0);
      wconv_t<<<dim3(FF / 32, DM / 32, 1), tb, 0, stream>>>(su_l, sguh, sgul, DM, FF, 1, 0, 0);
      wconv_t<<<dim3(DM / 32, FF / 32, 1), tb, 0, stream>>>(sd_l, sdh, sdl, FF, DM, -1, 0, 0);
      wconv_t<<<dim3(FF / 32, DM / 32, NEXP), tb, 0, stream>>>(
          eg_l, eguh, egul, DM, FF, 0, (long)DM * FF, (long)FF2 * DM);
      wconv_t<<<dim3(FF / 32, DM / 32, NEXP), tb, 0, stream>>>(
          eu_l, eguh, egul, DM, FF, 1, (long)DM * FF, (long)FF2 * DM);

      f2bsplit_k<<<gND, 256, 0, stream>>>(xc, xnh, xnl, ND);
      // shared expert: fused gu+silu -> hb[0..NTOK), down atomic into xc
      gemm3_nt<5><<<dim3(FF2 >> 7, NTOK >> 7, 1), 256, 0, stream>>>(
          xnh, xnl, sguh, sgul, nullptr, NTOK, FF2, DM, DM, DM, 0, 0, 0, 1, hbh, hbl);
      gemm3_nt<3><<<dim3(DM >> 7, NTOK >> 7, 4), 256, 0, stream>>>(
          hbh, hbl, sdh, sdl, xc, NTOK, DM, FF, FF, FF, 0, 0, 0, 4, nullptr, nullptr);
      // all 4 routed experts batched (z = expert)
      gemm3i_nt<5><<<dim3(FF2 >> 7, NTOK >> 7, NEXP), 256, 0, stream>>>(
          xnh, xnl, eguh, egul, nullptr, FF2, DM, DM, DM, FF2,
          permb, cntb, cbaseb, 1, (long)FF2 * DM, hbh, hbl, comb);
      wconv_t<<<dim3(DM / 32, FF / 32, NEXP), tb, 0, stream>>>(
          ed_l, edh, edl, FF, DM, -1, (long)FF * DM, (long)DM * FF);
      gemm3i_nt<1><<<dim3(DM >> 7, NTOK >> 7, NEXP * 2), 256, 0, stream>>>(
          hbh, hbl, edh, edl, xc, DM, FF, FF, FF, DM,
          permb, cntb, cbaseb, 2, (long)DM * FF, nullptr, nullptr, nullptr);
    } else {
      // layer-1: plain bf16 path -> convert hi only (skip lo writes)
      wconv_t<<<dim3(FF / 32, DM / 32, 1), tb, 0, stream>>>(sg_l, sguh, nullptr, DM, FF, 0, 0, 0);
      wconv_t<<<dim3(FF / 32, DM / 32, 1), tb, 0, stream>>>(su_l, sguh, nullptr, DM, FF, 1, 0, 0);
      wconv_t<<<dim3(DM / 32, FF / 32, 1), tb, 0, stream>>>(sd_l, sdh, nullptr, FF, DM, -1, 0, 0);
      wconv_t<<<dim3(FF / 32, DM / 32, NEXP), tb, 0, stream>>>(
          eg_l, eguh, nullptr, DM, FF, 0, (long)DM * FF, (long)FF2 * DM);
      wconv_t<<<dim3(FF / 32, DM / 32, NEXP), tb, 0, stream>>>(
          eu_l, eguh, nullptr, DM, FF, 1, (long)DM * FF, (long)FF2 * DM);

      f2b_k<<<gND, 256, 0, stream>>>(xc, xnh, ND);
      gemm_nt<5><<<dim3(FF2 >> 7, NTOK >> 7, 1), 256, 0, stream>>>(
          xnh, sguh, nullptr, NTOK, FF2, DM, DM, DM, 0, 0, 0, 1, hbh);
      gemm_nt<3><<<dim3(DM >> 7, NTOK >> 7, 4), 256, 0, stream>>>(
          hbh, sdh, xc, NTOK, DM, FF, FF, FF, 0, 0, 0, 4, nullptr);
      gemmi_nt<5><<<dim3(FF2 >> 7, NTOK >> 7, NEXP), 256, 0, stream>>>(
          xnh, eguh, nullptr, FF2, DM, DM, DM, FF2,
          permb, cntb, cbaseb, 1, (long)FF2 * DM, hbh, comb);
      wconv_t<<<dim3(DM / 32, FF / 32, NEXP), tb, 0, stream>>>(
          ed_l, edh, nullptr, FF, DM, -1, (long)FF * DM, (long)DM * FF);
      gemmi_nt<3><<<dim3(DM >> 7, NTOK >> 7, NEXP * 2), 256, 0, stream>>>(
          hbh, edh, xc, DM, FF, FF, FF, DM,
          permb, cntb, cbaseb, 2, (long)DM * FF, nullptr, nullptr);
    }
    ln_k<<<NTOK, 256, 0, stream>>>(xc, ln2_g + l * DM, ln2_b + l * DM, xc, nullptr, nullptr);
  }
}